// Round 1
// baseline (1593.929 us; speedup 1.0000x reference)
//
#include <hip/hip_runtime.h>
#include <hip/hip_bf16.h>
#include <cmath>

// Problem constants
#define BB 4
#define TT 16
#define HH 32
#define WW 64
#define DD 256
#define NHEAD 8
#define EE 32
#define MP 64      // M_PANEL
#define ML 16      // M_LAST
#define SPAT 32768 // TT*HH*WW
#define S2D 512    // TT*HH

// d_ws layout (float offsets)
constexpr size_t OFF_WRE  = 0;        // [ws][f] 64x16
constexpr size_t OFF_WIM  = 1024;
constexpr size_t OFF_FTRE = 2048;     // [p][t] 64x16
constexpr size_t OFF_FTIM = 3072;
constexpr size_t OFF_FHRE = 4096;     // [p][hs] 64x32
constexpr size_t OFF_FHIM = 6144;
constexpr size_t OFF_CW   = 8192;     // [f][ws] 16x64
constexpr size_t OFF_QR   = 16384;                  // [b*256+d][sp] 33.5M floats (reused for o)
constexpr size_t OFF_FW   = OFF_QR + 33554432;      // [bd][s][f] cplx 16.8M floats
constexpr size_t OFF_X    = OFF_FW + 16777216;      // [bd][p][f] cplx 2.1M floats
constexpr size_t OFF_V    = OFF_X + 2097152;        // [bd][p][f] cplx 2.1M floats

// ---------------- K0: twiddle tables ----------------
__global__ __launch_bounds__(256) void k0_tables(const int* __restrict__ panel, float* __restrict__ tab) {
  __shared__ int kt[MP], kh[MP];
  int tid = threadIdx.x;
  if (tid < MP) { int s = panel[tid]; kt[tid] = s >> 5; kh[tid] = s & 31; }
  __syncthreads();
  const double PI2 = 6.283185307179586476925286766559;
  // W: e^{-2pi i ws f/64}
  for (int i = tid; i < 1024; i += 256) {
    int ws = i >> 4, f = i & 15;
    double a = -PI2 * (double)((ws * f) & 63) / 64.0;
    tab[OFF_WRE + i] = (float)cos(a);
    tab[OFF_WIM + i] = (float)sin(a);
  }
  // Ft: e^{-2pi i t kt[p]/16}
  for (int i = tid; i < 1024; i += 256) {
    int p = i >> 4, t = i & 15;
    double a = -PI2 * (double)((t * kt[p]) & 15) / 16.0;
    tab[OFF_FTRE + i] = (float)cos(a);
    tab[OFF_FTIM + i] = (float)sin(a);
  }
  // Fh: e^{-2pi i hs kh[p]/32}
  for (int i = tid; i < 2048; i += 256) {
    int p = i >> 5, hs = i & 31;
    double a = -PI2 * (double)((hs * kh[p]) & 31) / 32.0;
    tab[OFF_FHRE + i] = (float)cos(a);
    tab[OFF_FHIM + i] = (float)sin(a);
  }
  // Cw: f==0 -> 1/64 else 2cos(2pi f ws/64)/64
  for (int i = tid; i < 1024; i += 256) {
    int f = i >> 6, ws = i & 63;
    double a = PI2 * (double)((f * ws) & 63) / 64.0;
    tab[OFF_CW + i] = (f == 0) ? (1.0f / 64.0f) : (float)(2.0 * cos(a) / 64.0);
  }
}

// ---------------- K1: Q = x @ Wq + bq, written as [b][d][sp] ----------------
__global__ __launch_bounds__(256) void k1_qgemm(const float* __restrict__ x, const float* __restrict__ Wq,
                                                const float* __restrict__ bq, float* __restrict__ Qr) {
  __shared__ float As[16][65]; // [k][row]
  __shared__ float Bs[16][64]; // [k][col]
  int n0 = blockIdx.x * 64;      // global row (b,sp)
  int b = n0 >> 15;
  int sp0 = n0 & 32767;
  int d0 = blockIdx.y * 64;
  int tid = threadIdx.x;
  int ty = tid & 15;  // sp sub-tile (x4)  -- fast => coalesced writes along sp
  int tx = tid >> 4;  // d sub-tile (x4)
  float acc[4][4];
  #pragma unroll
  for (int j = 0; j < 4; j++) {
    float bv = bq[d0 + tx * 4 + j];
    #pragma unroll
    for (int i = 0; i < 4; i++) acc[i][j] = bv;
  }
  for (int k0 = 0; k0 < 256; k0 += 16) {
    #pragma unroll
    for (int l = 0; l < 4; l++) {
      int idx = tid + l * 256;
      int r = idx >> 4, kk = idx & 15;
      As[kk][r] = x[(size_t)(n0 + r) * 256 + k0 + kk];
    }
    #pragma unroll
    for (int l = 0; l < 4; l++) {
      int idx = tid + l * 256;
      int kk = idx >> 6, dd = idx & 63;
      Bs[kk][dd] = Wq[(size_t)(k0 + kk) * 256 + d0 + dd];
    }
    __syncthreads();
    #pragma unroll
    for (int kk = 0; kk < 16; kk++) {
      float a[4], bb[4];
      #pragma unroll
      for (int i = 0; i < 4; i++) a[i] = As[kk][ty * 4 + i];
      #pragma unroll
      for (int j = 0; j < 4; j++) bb[j] = Bs[kk][tx * 4 + j];
      #pragma unroll
      for (int i = 0; i < 4; i++)
        #pragma unroll
        for (int j = 0; j < 4; j++) acc[i][j] += a[i] * bb[j];
    }
    __syncthreads();
  }
  #pragma unroll
  for (int j = 0; j < 4; j++) {
    float4 v = make_float4(acc[0][j], acc[1][j], acc[2][j], acc[3][j]);
    *reinterpret_cast<float4*>(&Qr[(size_t)(b * 256 + d0 + tx * 4 + j) * SPAT + sp0 + ty * 4]) = v;
  }
}

// ---------------- K2: WS-axis DFT (f<16): Fw[bd][s][f] ----------------
__global__ __launch_bounds__(512) void k2_wsdft(const float* __restrict__ Qr, const float* __restrict__ tab,
                                                float* __restrict__ Fw) {
  __shared__ float q[32][64];
  __shared__ float wre[64][16], wim[64][16];
  int bd = blockIdx.x >> 4;
  int t = blockIdx.x & 15;
  int tid = threadIdx.x;
  for (int i = tid; i < 2048; i += 512) q[i >> 6][i & 63] = Qr[(size_t)bd * SPAT + t * 2048 + i];
  for (int i = tid; i < 1024; i += 512) {
    wre[i >> 4][i & 15] = tab[OFF_WRE + i];
    wim[i >> 4][i & 15] = tab[OFF_WIM + i];
  }
  __syncthreads();
  int hs = tid >> 4, f = tid & 15;
  float sre = 0.f, sim = 0.f;
  #pragma unroll
  for (int ws = 0; ws < 64; ws++) {
    float qv = q[hs][ws];
    sre += qv * wre[ws][f];
    sim += qv * wim[ws][f];
  }
  size_t o = ((size_t)bd * S2D + t * 32 + hs) * ML + f;
  reinterpret_cast<float2*>(Fw)[o] = make_float2(sre, sim);
}

// ---------------- K3: panel DFT over (t,hs): X[bd][p][f] ----------------
__global__ __launch_bounds__(1024) void k3_panel(const float* __restrict__ Fw, const float* __restrict__ tab,
                                                 float* __restrict__ X) {
  __shared__ float2 fw[512][16]; // 64KB
  __shared__ float2 ft[64][16];
  __shared__ float2 fh[64][32];
  int bd = blockIdx.x;
  int tid = threadIdx.x;
  const float2* FwV = reinterpret_cast<const float2*>(Fw) + (size_t)bd * S2D * ML;
  for (int i = tid; i < 8192; i += 1024) fw[i >> 4][i & 15] = FwV[i];
  if (tid < 1024) { int i = tid; ft[i >> 4][i & 15] = make_float2(tab[OFF_FTRE + i], tab[OFF_FTIM + i]); }
  for (int i = tid; i < 2048; i += 1024) fh[i >> 5][i & 31] = make_float2(tab[OFF_FHRE + i], tab[OFF_FHIM + i]);
  __syncthreads();
  int p = tid >> 4, f = tid & 15;
  float ar = 0.f, ai = 0.f;
  for (int t = 0; t < 16; t++) {
    float2 et = ft[p][t];
    #pragma unroll
    for (int hs = 0; hs < 32; hs++) {
      float2 eh = fh[p][hs];
      float er = et.x * eh.x - et.y * eh.y;
      float ei = et.x * eh.y + et.y * eh.x;
      float2 v = fw[t * 32 + hs][f];
      ar += v.x * er - v.y * ei;
      ai += v.x * ei + v.y * er;
    }
  }
  reinterpret_cast<float2*>(X)[((size_t)bd * MP + p) * ML + f] = make_float2(ar, ai);
}

// ---------------- K3b: mode mix out_sel = sum_i x_sel * w ----------------
__global__ __launch_bounds__(512) void k3b_mix(const float* __restrict__ X, const float* __restrict__ wreal,
                                               const float* __restrict__ wimag, float* __restrict__ V) {
  __shared__ float2 xs[4][32][16]; // 16KB
  int h = blockIdx.x >> 6;
  int p = blockIdx.x & 63;
  int tid = threadIdx.x;
  const float2* Xv = reinterpret_cast<const float2*>(X);
  for (int i = tid; i < 2048; i += 512) {
    int b = i >> 9, ii = (i >> 4) & 31, f = i & 15;
    xs[b][ii][f] = Xv[((size_t)(b * 256 + h * 32 + ii) * MP + p) * ML + f];
  }
  __syncthreads();
  int o = tid >> 4, f = tid & 15;
  float accr[4] = {0, 0, 0, 0}, acci[4] = {0, 0, 0, 0};
  for (int i = 0; i < 32; i++) {
    size_t wofs = ((((size_t)h * 32 + i) * 32 + o) * MP + p) * ML + f;
    float wr = wreal[wofs], wi = wimag[wofs];
    #pragma unroll
    for (int b = 0; b < 4; b++) {
      float2 xv = xs[b][i][f];
      accr[b] += xv.x * wr - xv.y * wi;
      acci[b] += xv.x * wi + xv.y * wr;
    }
  }
  #pragma unroll
  for (int b = 0; b < 4; b++)
    reinterpret_cast<float2*>(V)[((size_t)(b * 256 + h * 32 + o) * MP + p) * ML + f] =
        make_float2(accr[b], acci[b]);
}

// ---------------- K4: inverse spatial DFT (real) + ws cosine expansion ----------------
// G[s][f] = (1/512) sum_p (Vre*er + Vim*ei), (er,ei)=Ft[p][t]*Fh[p][hs] (fwd sign)
// o[s][ws] = sum_f G[s][f] * Cw[f][ws]
__global__ __launch_bounds__(256) void k4_inv(const float* __restrict__ V, const float* __restrict__ tab,
                                              float* __restrict__ obuf) {
  __shared__ float2 vl[64][16];
  __shared__ float2 ft[64][16];
  __shared__ float2 fh[64][32];
  __shared__ float cw[16][64];
  __shared__ float G[512][17]; // pad to kill bank conflicts
  int bd = blockIdx.x;
  int tid = threadIdx.x;
  const float2* Vv = reinterpret_cast<const float2*>(V) + (size_t)bd * MP * ML;
  for (int i = tid; i < 1024; i += 256) {
    vl[i >> 4][i & 15] = Vv[i];
    ft[i >> 4][i & 15] = make_float2(tab[OFF_FTRE + i], tab[OFF_FTIM + i]);
    cw[i >> 6][i & 63] = tab[OFF_CW + i];
  }
  for (int i = tid; i < 2048; i += 256) fh[i >> 5][i & 31] = make_float2(tab[OFF_FHRE + i], tab[OFF_FHIM + i]);
  __syncthreads();
  #pragma unroll
  for (int sidx = 0; sidx < 2; sidx++) {
    int s = tid * 2 + sidx;
    int t = s >> 5, hs = s & 31;
    float g[16];
    #pragma unroll
    for (int f = 0; f < 16; f++) g[f] = 0.f;
    for (int p = 0; p < 64; p++) {
      float2 et = ft[p][t], eh = fh[p][hs];
      float er = et.x * eh.x - et.y * eh.y;
      float ei = et.x * eh.y + et.y * eh.x;
      #pragma unroll
      for (int f = 0; f < 16; f++) {
        float2 v = vl[p][f];
        g[f] += v.x * er + v.y * ei;
      }
    }
    #pragma unroll
    for (int f = 0; f < 16; f++) G[s][f] = g[f] * (1.f / 512.f);
  }
  __syncthreads();
  int ws = tid & 63, sg = tid >> 6;
  for (int s = sg; s < 512; s += 4) {
    float acc = 0.f;
    #pragma unroll
    for (int f = 0; f < 16; f++) acc += G[s][f] * cw[f][ws];
    obuf[(size_t)bd * SPAT + s * 64 + ws] = acc;
  }
}

// ---------------- K5: out = o @ Wo + bo (o stored [b][c][sp]) ----------------
__global__ __launch_bounds__(256) void k5_ogemm(const float* __restrict__ obuf, const float* __restrict__ Wo,
                                                const float* __restrict__ bo, float* __restrict__ out) {
  __shared__ float As[16][65]; // [k][row]
  __shared__ float Bs[16][64];
  int n0 = blockIdx.x * 64;
  int b = n0 >> 15;
  int sp0 = n0 & 32767;
  int d0 = blockIdx.y * 64;
  int tid = threadIdx.x;
  int tx = tid & 15;  // d sub-tile (x4) -- fast => coalesced writes along d
  int ty = tid >> 4;  // sp sub-tile (x4)
  float acc[4][4];
  #pragma unroll
  for (int j = 0; j < 4; j++) {
    float bv = bo[d0 + tx * 4 + j];
    #pragma unroll
    for (int i = 0; i < 4; i++) acc[i][j] = bv;
  }
  for (int k0 = 0; k0 < 256; k0 += 16) {
    #pragma unroll
    for (int l = 0; l < 4; l++) {
      int idx = tid + l * 256;
      int cc = idx >> 6, r = idx & 63;
      As[cc][r] = obuf[(size_t)(b * 256 + k0 + cc) * SPAT + sp0 + r];
    }
    #pragma unroll
    for (int l = 0; l < 4; l++) {
      int idx = tid + l * 256;
      int cc = idx >> 6, dd = idx & 63;
      Bs[cc][dd] = Wo[(size_t)(k0 + cc) * 256 + d0 + dd];
    }
    __syncthreads();
    #pragma unroll
    for (int kk = 0; kk < 16; kk++) {
      float a[4], bb[4];
      #pragma unroll
      for (int i = 0; i < 4; i++) a[i] = As[kk][ty * 4 + i];
      #pragma unroll
      for (int j = 0; j < 4; j++) bb[j] = Bs[kk][tx * 4 + j];
      #pragma unroll
      for (int i = 0; i < 4; i++)
        #pragma unroll
        for (int j = 0; j < 4; j++) acc[i][j] += a[i] * bb[j];
    }
    __syncthreads();
  }
  #pragma unroll
  for (int i = 0; i < 4; i++) {
    float4 v = make_float4(acc[i][0], acc[i][1], acc[i][2], acc[i][3]);
    *reinterpret_cast<float4*>(&out[(size_t)(b * SPAT + sp0 + ty * 4 + i) * 256 + d0 + tx * 4]) = v;
  }
}

extern "C" void kernel_launch(void* const* d_in, const int* in_sizes, int n_in,
                              void* d_out, int out_size, void* d_ws, size_t ws_size,
                              hipStream_t stream) {
  const float* x  = (const float*)d_in[0];
  const float* Wq = (const float*)d_in[1];
  const float* bq = (const float*)d_in[2];
  // d_in[3..6] = Wk,bk,Wv,bv -- dead in the reference, skipped
  const float* Wo = (const float*)d_in[7];
  const float* bo = (const float*)d_in[8];
  const float* wr = (const float*)d_in[9];
  const float* wi = (const float*)d_in[10];
  const int* panel = (const int*)d_in[11];
  float* ws = (float*)d_ws;
  float* out = (float*)d_out;

  hipLaunchKernelGGL(k0_tables, dim3(1), dim3(256), 0, stream, panel, ws);
  hipLaunchKernelGGL(k1_qgemm, dim3(2048, 4), dim3(256), 0, stream, x, Wq, bq, ws + OFF_QR);
  hipLaunchKernelGGL(k2_wsdft, dim3(16384), dim3(512), 0, stream, ws + OFF_QR, ws, ws + OFF_FW);
  hipLaunchKernelGGL(k3_panel, dim3(1024), dim3(1024), 0, stream, ws + OFF_FW, ws, ws + OFF_X);
  hipLaunchKernelGGL(k3b_mix, dim3(512), dim3(512), 0, stream, ws + OFF_X, wr, wi, ws + OFF_V);
  hipLaunchKernelGGL(k4_inv, dim3(1024), dim3(256), 0, stream, ws + OFF_V, ws, ws + OFF_QR);
  hipLaunchKernelGGL(k5_ogemm, dim3(2048, 4), dim3(256), 0, stream, ws + OFF_QR, Wo, bo, out);
}

// Round 2
// 830.761 us; speedup vs baseline: 1.9186x; 1.9186x over previous
//
#include <hip/hip_runtime.h>
#include <hip/hip_bf16.h>
#include <cmath>

// Problem constants
#define BB 4
#define TT 16
#define HH 32
#define WW 64
#define DD 256
#define NHEAD 8
#define EE 32
#define MP 64      // M_PANEL
#define ML 16      // M_LAST
#define SPAT 32768 // TT*HH*WW
#define S2D 512    // TT*HH

// d_ws layout (float offsets)
constexpr size_t OFF_FTRE = 0;        // [p][t] 64x16
constexpr size_t OFF_FTIM = 1024;
constexpr size_t OFF_FHRE = 2048;     // [p][hs] 64x32
constexpr size_t OFF_FHIM = 4096;
constexpr size_t OFF_CW   = 6144;     // [f][ws] 16x64
constexpr size_t OFF_W64I = 7168;     // [ws][f2] 64x32 interleaved re,im
constexpr size_t OFF_W16  = 9216;     // [t][kt] float2 16x16
constexpr size_t OFF_FHT  = 9728;     // [hs][p] float2 32x64
constexpr size_t OFF_QR   = 16384;                  // [b*256+d][sp] 33.5M floats (reused for o)
constexpr size_t OFF_FW   = OFF_QR + 33554432;      // [bd][s][f] cplx 16.8M floats (reused in-place for U)
constexpr size_t OFF_X    = OFF_FW + 16777216;      // [bd][p][f] cplx 2.1M floats
constexpr size_t OFF_V    = OFF_X + 2097152;        // [bd][p][f] cplx 2.1M floats

// ---------------- K0: twiddle tables ----------------
__global__ __launch_bounds__(256) void k0_tables(const int* __restrict__ panel, float* __restrict__ tab) {
  __shared__ int kt[MP], kh[MP];
  int tid = threadIdx.x;
  if (tid < MP) { int s = panel[tid]; kt[tid] = s >> 5; kh[tid] = s & 31; }
  __syncthreads();
  const double PI2 = 6.283185307179586476925286766559;
  for (int i = tid; i < 1024; i += 256) {  // FT [p][t]
    int p = i >> 4, t = i & 15;
    double a = -PI2 * (double)((t * kt[p]) & 15) / 16.0;
    tab[OFF_FTRE + i] = (float)cos(a);
    tab[OFF_FTIM + i] = (float)sin(a);
  }
  for (int i = tid; i < 2048; i += 256) {  // FH [p][hs]
    int p = i >> 5, hs = i & 31;
    double a = -PI2 * (double)((hs * kh[p]) & 31) / 32.0;
    tab[OFF_FHRE + i] = (float)cos(a);
    tab[OFF_FHIM + i] = (float)sin(a);
  }
  for (int i = tid; i < 1024; i += 256) {  // CW [f][ws]
    int f = i >> 6, wsx = i & 63;
    double a = PI2 * (double)((f * wsx) & 63) / 64.0;
    tab[OFF_CW + i] = (f == 0) ? (1.0f / 64.0f) : (float)(2.0 * cos(a) / 64.0);
  }
  for (int i = tid; i < 2048; i += 256) {  // W64I [ws][f2]
    int wsx = i >> 5, f2 = i & 31; int f = f2 >> 1;
    double a = -PI2 * (double)((wsx * f) & 63) / 64.0;
    tab[OFF_W64I + i] = (f2 & 1) ? (float)sin(a) : (float)cos(a);
  }
  if (tid < 256) {                         // W16 [t][kt] float2
    int t = tid >> 4, k = tid & 15;
    double a = -PI2 * (double)((t * k) & 15) / 16.0;
    tab[OFF_W16 + 2 * tid]     = (float)cos(a);
    tab[OFF_W16 + 2 * tid + 1] = (float)sin(a);
  }
  for (int i = tid; i < 2048; i += 256) {  // FHT [hs][p] float2
    int hs = i >> 6, p = i & 63;
    double a = -PI2 * (double)((hs * kh[p]) & 31) / 32.0;
    tab[OFF_FHT + 2 * i]     = (float)cos(a);
    tab[OFF_FHT + 2 * i + 1] = (float)sin(a);
  }
}

// ---------------- K1: Q = x @ Wq + bq, written as [b][d][sp] ----------------
__global__ __launch_bounds__(256) void k1_qgemm(const float* __restrict__ x, const float* __restrict__ Wq,
                                                const float* __restrict__ bq, float* __restrict__ Qr) {
  __shared__ float As[16][65]; // [k][row]
  __shared__ float Bs[16][64]; // [k][col]
  int n0 = blockIdx.x * 64;      // global row (b,sp)
  int b = n0 >> 15;
  int sp0 = n0 & 32767;
  int d0 = blockIdx.y * 64;
  int tid = threadIdx.x;
  int ty = tid & 15;  // sp sub-tile (x4)
  int tx = tid >> 4;  // d sub-tile (x4)
  float acc[4][4];
  #pragma unroll
  for (int j = 0; j < 4; j++) {
    float bv = bq[d0 + tx * 4 + j];
    #pragma unroll
    for (int i = 0; i < 4; i++) acc[i][j] = bv;
  }
  for (int k0 = 0; k0 < 256; k0 += 16) {
    #pragma unroll
    for (int l = 0; l < 4; l++) {
      int idx = tid + l * 256;
      int r = idx >> 4, kk = idx & 15;
      As[kk][r] = x[(size_t)(n0 + r) * 256 + k0 + kk];
    }
    #pragma unroll
    for (int l = 0; l < 4; l++) {
      int idx = tid + l * 256;
      int kk = idx >> 6, dd = idx & 63;
      Bs[kk][dd] = Wq[(size_t)(k0 + kk) * 256 + d0 + dd];
    }
    __syncthreads();
    #pragma unroll
    for (int kk = 0; kk < 16; kk++) {
      float a[4], bb[4];
      #pragma unroll
      for (int i = 0; i < 4; i++) a[i] = As[kk][ty * 4 + i];
      #pragma unroll
      for (int j = 0; j < 4; j++) bb[j] = Bs[kk][tx * 4 + j];
      #pragma unroll
      for (int i = 0; i < 4; i++)
        #pragma unroll
        for (int j = 0; j < 4; j++) acc[i][j] += a[i] * bb[j];
    }
    __syncthreads();
  }
  #pragma unroll
  for (int j = 0; j < 4; j++) {
    float4 v = make_float4(acc[0][j], acc[1][j], acc[2][j], acc[3][j]);
    *reinterpret_cast<float4*>(&Qr[(size_t)(b * 256 + d0 + tx * 4 + j) * SPAT + sp0 + ty * 4]) = v;
  }
}

// ---------------- K2g: ws-DFT as real GEMM: Fw[s][f2] = Q[s][ws] * W64I[ws][f2] ----------------
__global__ __launch_bounds__(256) void k2_wsgemm(const float* __restrict__ Qr, const float* __restrict__ tab,
                                                 float* __restrict__ Fw) {
  __shared__ float QT[64][129]; // [ws][s] transposed tile, +1-pad -> 2-way max on writes
  __shared__ float WL[64][32];  // [ws][f2]
  int bd = blockIdx.x >> 2;
  int s0 = (blockIdx.x & 3) * 128;
  int tid = threadIdx.x;
  const float* qbase = Qr + (size_t)bd * SPAT + (size_t)s0 * 64;
  for (int i = tid; i < 8192; i += 256) {
    int wsx = i & 63, s = i >> 6;
    QT[wsx][s] = qbase[(size_t)s * 64 + wsx]; // global coalesced (consecutive wsx)
  }
  for (int i = tid; i < 2048; i += 256) WL[i >> 5][i & 31] = tab[OFF_W64I + i];
  __syncthreads();
  int sq = tid & 31, fq = tid >> 5; // 32 s-quads x 8 f2-quads
  float acc[4][4];
  #pragma unroll
  for (int i = 0; i < 4; i++)
    #pragma unroll
    for (int j = 0; j < 4; j++) acc[i][j] = 0.f;
  #pragma unroll 8
  for (int wsx = 0; wsx < 64; wsx++) {
    float4 qv = *reinterpret_cast<const float4*>(&QT[wsx][sq * 4]);
    float4 wv = *reinterpret_cast<const float4*>(&WL[wsx][fq * 4]);
    acc[0][0] += qv.x * wv.x; acc[0][1] += qv.x * wv.y; acc[0][2] += qv.x * wv.z; acc[0][3] += qv.x * wv.w;
    acc[1][0] += qv.y * wv.x; acc[1][1] += qv.y * wv.y; acc[1][2] += qv.y * wv.z; acc[1][3] += qv.y * wv.w;
    acc[2][0] += qv.z * wv.x; acc[2][1] += qv.z * wv.y; acc[2][2] += qv.z * wv.z; acc[2][3] += qv.z * wv.w;
    acc[3][0] += qv.w * wv.x; acc[3][1] += qv.w * wv.y; acc[3][2] += qv.w * wv.z; acc[3][3] += qv.w * wv.w;
  }
  #pragma unroll
  for (int i = 0; i < 4; i++) {
    float4 v = make_float4(acc[i][0], acc[i][1], acc[i][2], acc[i][3]);
    *reinterpret_cast<float4*>(&Fw[((size_t)bd * 512 + s0 + sq * 4 + i) * 32 + fq * 4]) = v;
  }
}

// ---------------- K3a: t-DFT over all kt-hat, IN-PLACE in Fw buffer ----------------
// U[bd][kt][hs][f] = sum_t W16[kt][t] * Fw[bd][t*32+hs][f]
__global__ __launch_bounds__(256) void k3a_tdft(float* __restrict__ FwU, const float* __restrict__ tab) {
  __shared__ float2 W16L[16][16];
  int bd = blockIdx.x;
  int tid = threadIdx.x;
  W16L[tid >> 4][tid & 15] = reinterpret_cast<const float2*>(tab + OFF_W16)[tid];
  __syncthreads();
  float2* base = reinterpret_cast<float2*>(FwU) + (size_t)bd * 8192;
  float2 a0[16], a1[16];
  #pragma unroll
  for (int k = 0; k < 16; k++) { a0[k] = make_float2(0.f, 0.f); a1[k] = make_float2(0.f, 0.f); }
  #pragma unroll
  for (int t = 0; t < 16; t++) {
    float2 v0 = base[t * 512 + tid];
    float2 v1 = base[t * 512 + 256 + tid];
    #pragma unroll
    for (int k = 0; k < 16; k++) {
      float2 w = W16L[t][k];
      a0[k].x += w.x * v0.x - w.y * v0.y; a0[k].y += w.x * v0.y + w.y * v0.x;
      a1[k].x += w.x * v1.x - w.y * v1.y; a1[k].y += w.x * v1.y + w.y * v1.x;
    }
  }
  // each thread writes only the columns it read -> in-place safe
  #pragma unroll
  for (int k = 0; k < 16; k++) {
    base[k * 512 + tid] = a0[k];
    base[k * 512 + 256 + tid] = a1[k];
  }
}

// ---------------- K3s: selected hs-reduction: X[bd][p][f] = sum_hs fh[p][hs] * U[bd][kt[p]][hs][f] ----------------
__global__ __launch_bounds__(1024) void k3s_sel(const float* __restrict__ U, const float* __restrict__ tab,
                                                const int* __restrict__ panel, float* __restrict__ X) {
  __shared__ float2 fhT[32][64];
  __shared__ int ktl[64];
  int bd = blockIdx.x;
  int tid = threadIdx.x;
  for (int i = tid; i < 2048; i += 1024) fhT[i >> 6][i & 63] = reinterpret_cast<const float2*>(tab + OFF_FHT)[i];
  if (tid < 64) ktl[tid] = panel[tid] >> 5;
  __syncthreads();
  int p = tid >> 4, f = tid & 15;
  int kt = ktl[p];
  const float2* ub = reinterpret_cast<const float2*>(U) + (size_t)bd * 8192 + (size_t)kt * 512 + f;
  float ar = 0.f, ai = 0.f;
  #pragma unroll 8
  for (int hs = 0; hs < 32; hs++) {
    float2 e = fhT[hs][p];
    float2 u = ub[hs * 16];
    ar += u.x * e.x - u.y * e.y;
    ai += u.x * e.y + u.y * e.x;
  }
  reinterpret_cast<float2*>(X)[(size_t)bd * 1024 + tid] = make_float2(ar, ai);
}

// ---------------- K3b: mode mix out_sel = sum_i x_sel * w ----------------
__global__ __launch_bounds__(512) void k3b_mix(const float* __restrict__ X, const float* __restrict__ wreal,
                                               const float* __restrict__ wimag, float* __restrict__ V) {
  __shared__ float2 xs[4][32][16]; // 16KB
  int h = blockIdx.x >> 6;
  int p = blockIdx.x & 63;
  int tid = threadIdx.x;
  const float2* Xv = reinterpret_cast<const float2*>(X);
  for (int i = tid; i < 2048; i += 512) {
    int b = i >> 9, ii = (i >> 4) & 31, f = i & 15;
    xs[b][ii][f] = Xv[((size_t)(b * 256 + h * 32 + ii) * MP + p) * ML + f];
  }
  __syncthreads();
  int o = tid >> 4, f = tid & 15;
  float accr[4] = {0, 0, 0, 0}, acci[4] = {0, 0, 0, 0};
  for (int i = 0; i < 32; i++) {
    size_t wofs = ((((size_t)h * 32 + i) * 32 + o) * MP + p) * ML + f;
    float wr = wreal[wofs], wi = wimag[wofs];
    #pragma unroll
    for (int b = 0; b < 4; b++) {
      float2 xv = xs[b][i][f];
      accr[b] += xv.x * wr - xv.y * wi;
      acci[b] += xv.x * wi + xv.y * wr;
    }
  }
  #pragma unroll
  for (int b = 0; b < 4; b++)
    reinterpret_cast<float2*>(V)[((size_t)(b * 256 + h * 32 + o) * MP + p) * ML + f] =
        make_float2(accr[b], acci[b]);
}

// ---------------- K4: inverse spatial DFT (real) + ws cosine expansion ----------------
__global__ __launch_bounds__(256) void k4_inv(const float* __restrict__ V, const float* __restrict__ tab,
                                              float* __restrict__ obuf) {
  __shared__ float2 vl[64][16];
  __shared__ float2 ft[64][16];
  __shared__ float2 fh[64][32];
  __shared__ float cw[16][64];
  __shared__ float G[512][17];
  int bd = blockIdx.x;
  int tid = threadIdx.x;
  const float2* Vv = reinterpret_cast<const float2*>(V) + (size_t)bd * MP * ML;
  for (int i = tid; i < 1024; i += 256) {
    vl[i >> 4][i & 15] = Vv[i];
    ft[i >> 4][i & 15] = make_float2(tab[OFF_FTRE + i], tab[OFF_FTIM + i]);
    cw[i >> 6][i & 63] = tab[OFF_CW + i];
  }
  for (int i = tid; i < 2048; i += 256) fh[i >> 5][i & 31] = make_float2(tab[OFF_FHRE + i], tab[OFF_FHIM + i]);
  __syncthreads();
  #pragma unroll
  for (int sidx = 0; sidx < 2; sidx++) {
    int s = tid * 2 + sidx;
    int t = s >> 5, hs = s & 31;
    float g[16];
    #pragma unroll
    for (int f = 0; f < 16; f++) g[f] = 0.f;
    for (int p = 0; p < 64; p++) {
      float2 et = ft[p][t], eh = fh[p][hs];
      float er = et.x * eh.x - et.y * eh.y;
      float ei = et.x * eh.y + et.y * eh.x;
      #pragma unroll
      for (int f = 0; f < 16; f++) {
        float2 v = vl[p][f];
        g[f] += v.x * er + v.y * ei;
      }
    }
    #pragma unroll
    for (int f = 0; f < 16; f++) G[s][f] = g[f] * (1.f / 512.f);
  }
  __syncthreads();
  int wsx = tid & 63, sg = tid >> 6;
  for (int s = sg; s < 512; s += 4) {
    float acc = 0.f;
    #pragma unroll
    for (int f = 0; f < 16; f++) acc += G[s][f] * cw[f][wsx];
    obuf[(size_t)bd * SPAT + s * 64 + wsx] = acc;
  }
}

// ---------------- K5: out = o @ Wo + bo (o stored [b][c][sp]) ----------------
__global__ __launch_bounds__(256) void k5_ogemm(const float* __restrict__ obuf, const float* __restrict__ Wo,
                                                const float* __restrict__ bo, float* __restrict__ out) {
  __shared__ float As[16][65];
  __shared__ float Bs[16][64];
  int n0 = blockIdx.x * 64;
  int b = n0 >> 15;
  int sp0 = n0 & 32767;
  int d0 = blockIdx.y * 64;
  int tid = threadIdx.x;
  int tx = tid & 15;
  int ty = tid >> 4;
  float acc[4][4];
  #pragma unroll
  for (int j = 0; j < 4; j++) {
    float bv = bo[d0 + tx * 4 + j];
    #pragma unroll
    for (int i = 0; i < 4; i++) acc[i][j] = bv;
  }
  for (int k0 = 0; k0 < 256; k0 += 16) {
    #pragma unroll
    for (int l = 0; l < 4; l++) {
      int idx = tid + l * 256;
      int cc = idx >> 6, r = idx & 63;
      As[cc][r] = obuf[(size_t)(b * 256 + k0 + cc) * SPAT + sp0 + r];
    }
    #pragma unroll
    for (int l = 0; l < 4; l++) {
      int idx = tid + l * 256;
      int cc = idx >> 6, dd = idx & 63;
      Bs[cc][dd] = Wo[(size_t)(k0 + cc) * 256 + d0 + dd];
    }
    __syncthreads();
    #pragma unroll
    for (int kk = 0; kk < 16; kk++) {
      float a[4], bb[4];
      #pragma unroll
      for (int i = 0; i < 4; i++) a[i] = As[kk][ty * 4 + i];
      #pragma unroll
      for (int j = 0; j < 4; j++) bb[j] = Bs[kk][tx * 4 + j];
      #pragma unroll
      for (int i = 0; i < 4; i++)
        #pragma unroll
        for (int j = 0; j < 4; j++) acc[i][j] += a[i] * bb[j];
    }
    __syncthreads();
  }
  #pragma unroll
  for (int i = 0; i < 4; i++) {
    float4 v = make_float4(acc[i][0], acc[i][1], acc[i][2], acc[i][3]);
    *reinterpret_cast<float4*>(&out[(size_t)(b * SPAT + sp0 + ty * 4 + i) * 256 + d0 + tx * 4]) = v;
  }
}

extern "C" void kernel_launch(void* const* d_in, const int* in_sizes, int n_in,
                              void* d_out, int out_size, void* d_ws, size_t ws_size,
                              hipStream_t stream) {
  const float* x  = (const float*)d_in[0];
  const float* Wq = (const float*)d_in[1];
  const float* bq = (const float*)d_in[2];
  // d_in[3..6] = Wk,bk,Wv,bv -- dead in the reference, skipped
  const float* Wo = (const float*)d_in[7];
  const float* bo = (const float*)d_in[8];
  const float* wr = (const float*)d_in[9];
  const float* wi = (const float*)d_in[10];
  const int* panel = (const int*)d_in[11];
  float* ws = (float*)d_ws;
  float* out = (float*)d_out;

  hipLaunchKernelGGL(k0_tables, dim3(1), dim3(256), 0, stream, panel, ws);
  hipLaunchKernelGGL(k1_qgemm, dim3(2048, 4), dim3(256), 0, stream, x, Wq, bq, ws + OFF_QR);
  hipLaunchKernelGGL(k2_wsgemm, dim3(4096), dim3(256), 0, stream, ws + OFF_QR, ws, ws + OFF_FW);
  hipLaunchKernelGGL(k3a_tdft, dim3(1024), dim3(256), 0, stream, ws + OFF_FW, ws);
  hipLaunchKernelGGL(k3s_sel, dim3(1024), dim3(1024), 0, stream, ws + OFF_FW, ws, panel, ws + OFF_X);
  hipLaunchKernelGGL(k3b_mix, dim3(512), dim3(512), 0, stream, ws + OFF_X, wr, wi, ws + OFF_V);
  hipLaunchKernelGGL(k4_inv, dim3(1024), dim3(256), 0, stream, ws + OFF_V, ws, ws + OFF_QR);
  hipLaunchKernelGGL(k5_ogemm, dim3(2048, 4), dim3(256), 0, stream, ws + OFF_QR, Wo, bo, out);
}

// Round 3
// 457.144 us; speedup vs baseline: 3.4867x; 1.8173x over previous
//
#include <hip/hip_runtime.h>
#include <hip/hip_bf16.h>
#include <cmath>

// Problem constants
#define BB 4
#define TT 16
#define HH 32
#define WW 64
#define DD 256
#define NHEAD 8
#define EE 32
#define MP 64      // M_PANEL
#define ML 16      // M_LAST
#define SPAT 32768 // TT*HH*WW
#define S2D 512    // TT*HH

// d_ws layout (float offsets)
constexpr size_t OFF_FTRE = 0;        // [p][t] 64x16
constexpr size_t OFF_FTIM = 1024;
constexpr size_t OFF_FHRE = 2048;     // [p][hs] 64x32
constexpr size_t OFF_FHIM = 4096;
constexpr size_t OFF_CW   = 6144;     // [f][ws] 16x64
constexpr size_t OFF_W64I = 7168;     // [ws][f2] 64x32 interleaved re,im
constexpr size_t OFF_W16  = 9216;     // [t][kt] float2 16x16
constexpr size_t OFF_FHT  = 9728;     // [hs][p] float2 32x64
constexpr size_t OFF_QR   = 16384;                  // Qr fp32 [b*256+d][sp] (33.5M fl); later ob bf16 [b][sp][c]
constexpr size_t OFF_FW   = OFF_QR + 33554432;      // xb bf16 (k1 input) -> Fw/U cplx (k2/k3) -> gbuf fp32 (k4a)
constexpr size_t OFF_X    = OFF_FW + 33554432;      // [bd][p][f] cplx 2.1M floats
constexpr size_t OFF_V    = OFF_X + 2097152;        // [bd][p][f] cplx 2.1M floats
constexpr size_t OFF_WT   = OFF_V + 2097152;        // WqT bf16 65536 + WoT bf16 65536 (32768 floats total)

typedef short short8 __attribute__((ext_vector_type(8)));
typedef float f32x4 __attribute__((ext_vector_type(4)));

static __device__ __forceinline__ unsigned short f2bf(float x) {
  union { float f; unsigned u; } v; v.f = x;
  unsigned r = v.u + 0x7fffu + ((v.u >> 16) & 1u);
  return (unsigned short)(r >> 16);
}

static __device__ __forceinline__ void gl_lds16(const void* g, void* l) {
  __builtin_amdgcn_global_load_lds((const __attribute__((address_space(1))) void*)g,
                                   (__attribute__((address_space(3))) void*)l, 16, 0, 0);
}

// ---------------- K0: twiddle tables ----------------
__global__ __launch_bounds__(256) void k0_tables(const int* __restrict__ panel, float* __restrict__ tab) {
  __shared__ int kt[MP], kh[MP];
  int tid = threadIdx.x;
  if (tid < MP) { int s = panel[tid]; kt[tid] = s >> 5; kh[tid] = s & 31; }
  __syncthreads();
  const double PI2 = 6.283185307179586476925286766559;
  for (int i = tid; i < 1024; i += 256) {  // FT [p][t]
    int p = i >> 4, t = i & 15;
    double a = -PI2 * (double)((t * kt[p]) & 15) / 16.0;
    tab[OFF_FTRE + i] = (float)cos(a);
    tab[OFF_FTIM + i] = (float)sin(a);
  }
  for (int i = tid; i < 2048; i += 256) {  // FH [p][hs]
    int p = i >> 5, hs = i & 31;
    double a = -PI2 * (double)((hs * kh[p]) & 31) / 32.0;
    tab[OFF_FHRE + i] = (float)cos(a);
    tab[OFF_FHIM + i] = (float)sin(a);
  }
  for (int i = tid; i < 1024; i += 256) {  // CW [f][ws]
    int f = i >> 6, wsx = i & 63;
    double a = PI2 * (double)((f * wsx) & 63) / 64.0;
    tab[OFF_CW + i] = (f == 0) ? (1.0f / 64.0f) : (float)(2.0 * cos(a) / 64.0);
  }
  for (int i = tid; i < 2048; i += 256) {  // W64I [ws][f2]
    int wsx = i >> 5, f2 = i & 31; int f = f2 >> 1;
    double a = -PI2 * (double)((wsx * f) & 63) / 64.0;
    tab[OFF_W64I + i] = (f2 & 1) ? (float)sin(a) : (float)cos(a);
  }
  if (tid < 256) {                         // W16 [t][kt] float2
    int t = tid >> 4, k = tid & 15;
    double a = -PI2 * (double)((t * k) & 15) / 16.0;
    tab[OFF_W16 + 2 * tid]     = (float)cos(a);
    tab[OFF_W16 + 2 * tid + 1] = (float)sin(a);
  }
  for (int i = tid; i < 2048; i += 256) {  // FHT [hs][p] float2
    int hs = i >> 6, p = i & 63;
    double a = -PI2 * (double)((hs * kh[p]) & 31) / 32.0;
    tab[OFF_FHT + 2 * i]     = (float)cos(a);
    tab[OFF_FHT + 2 * i + 1] = (float)sin(a);
  }
}

// ---------------- conv_x: x fp32 -> xb bf16 ----------------
__global__ __launch_bounds__(256) void conv_x(const float* __restrict__ x, unsigned short* __restrict__ xb) {
  size_t i0 = ((size_t)blockIdx.x * 256 + threadIdx.x) * 8;
  float4 a = *reinterpret_cast<const float4*>(x + i0);
  float4 b = *reinterpret_cast<const float4*>(x + i0 + 4);
  short8 v;
  v[0] = (short)f2bf(a.x); v[1] = (short)f2bf(a.y); v[2] = (short)f2bf(a.z); v[3] = (short)f2bf(a.w);
  v[4] = (short)f2bf(b.x); v[5] = (short)f2bf(b.y); v[6] = (short)f2bf(b.z); v[7] = (short)f2bf(b.w);
  *reinterpret_cast<short8*>(xb + i0) = v;
}

// ---------------- conv_w: Wq/Wo fp32 [k][d] -> WT bf16 [d][k] ----------------
__global__ __launch_bounds__(256) void conv_w(const float* __restrict__ Wq, const float* __restrict__ Wo,
                                              unsigned short* __restrict__ wqt, unsigned short* __restrict__ wot) {
  __shared__ float tile[32][33];
  const float* src = blockIdx.z ? Wo : Wq;
  unsigned short* dst = blockIdx.z ? wot : wqt;
  int k0 = blockIdx.x * 32, d0 = blockIdx.y * 32;
  int tx = threadIdx.x & 31, r4 = threadIdx.x >> 5;
  #pragma unroll
  for (int it = 0; it < 4; it++) {
    int row = r4 + it * 8;
    tile[row][tx] = src[(size_t)(k0 + row) * 256 + d0 + tx];
  }
  __syncthreads();
  #pragma unroll
  for (int it = 0; it < 4; it++) {
    int row = r4 + it * 8;
    dst[(size_t)(d0 + row) * 256 + k0 + tx] = f2bf(tile[tx][row]);
  }
}

// ---------------- K1: Q = x @ Wq + bq via bf16 MFMA, out fp32 [b][d][sp] ----------------
__global__ __launch_bounds__(256) void k1_mfma(const unsigned short* __restrict__ xb,
                                               const unsigned short* __restrict__ wqt,
                                               const float* __restrict__ bq, float* __restrict__ Qr) {
  __shared__ unsigned short Al[128 * 64]; // 16KB, row=128B, XOR-swizzled
  __shared__ unsigned short Bl[64 * 64];  // 8KB
  int b = blockIdx.x >> 8, sp0 = (blockIdx.x & 255) << 7, d0 = blockIdx.y << 6;
  int tid = threadIdx.x;
  int lane = tid & 63, w = tid >> 6;
  int l15 = lane & 15, kg = lane >> 4;
  int swz = (l15 & 7) << 4;
  f32x4 acc[2][4];
  #pragma unroll
  for (int mi = 0; mi < 2; mi++)
    #pragma unroll
    for (int ni = 0; ni < 4; ni++) acc[mi][ni] = (f32x4){0.f, 0.f, 0.f, 0.f};
  const char* Abase = (const char*)(xb + ((size_t)b * 32768 + sp0) * 256);
  const char* Bbase = (const char*)(wqt + (size_t)d0 * 256);
  for (int k0 = 0; k0 < 256; k0 += 64) {
    #pragma unroll
    for (int it = 0; it < 4; it++) {
      int o = tid * 16 + it * 4096;
      int row = o >> 7, cb = o & 127;
      int scb = cb ^ ((row & 7) << 4);
      gl_lds16(Abase + (size_t)row * 512 + k0 * 2 + scb, (char*)Al + o);
    }
    #pragma unroll
    for (int it = 0; it < 2; it++) {
      int o = tid * 16 + it * 4096;
      int row = o >> 7, cb = o & 127;
      int scb = cb ^ ((row & 7) << 4);
      gl_lds16(Bbase + (size_t)row * 512 + k0 * 2 + scb, (char*)Bl + o);
    }
    __syncthreads();
    #pragma unroll
    for (int ks = 0; ks < 2; ks++) {
      int koff = (ks * 64 + kg * 16) ^ swz;
      short8 af[2], bfr[4];
      #pragma unroll
      for (int mi = 0; mi < 2; mi++)
        af[mi] = *(const short8*)((const char*)Al + (w * 32 + mi * 16 + l15) * 128 + koff);
      #pragma unroll
      for (int ni = 0; ni < 4; ni++)
        bfr[ni] = *(const short8*)((const char*)Bl + (ni * 16 + l15) * 128 + koff);
      #pragma unroll
      for (int mi = 0; mi < 2; mi++)
        #pragma unroll
        for (int ni = 0; ni < 4; ni++)
          acc[mi][ni] = __builtin_amdgcn_mfma_f32_16x16x32_bf16(af[mi], bfr[ni], acc[mi][ni], 0, 0, 0);
    }
    __syncthreads();
  }
  #pragma unroll
  for (int ni = 0; ni < 4; ni++) {
    float bqv = bq[d0 + ni * 16 + l15];
    size_t col = (size_t)(b * 256 + d0 + ni * 16 + l15);
    #pragma unroll
    for (int mi = 0; mi < 2; mi++) {
      f32x4 v = acc[mi][ni];
      size_t m = (size_t)sp0 + w * 32 + mi * 16 + kg * 4;
      *reinterpret_cast<float4*>(&Qr[col * SPAT + m]) =
          make_float4(v[0] + bqv, v[1] + bqv, v[2] + bqv, v[3] + bqv);
    }
  }
}

// ---------------- K2g: ws-DFT as real GEMM: Fw[s][f2] = Q[s][ws] * W64I[ws][f2] ----------------
__global__ __launch_bounds__(256) void k2_wsgemm(const float* __restrict__ Qr, const float* __restrict__ tab,
                                                 float* __restrict__ Fw) {
  __shared__ float QT[64][129];
  __shared__ float WL[64][32];
  int bd = blockIdx.x >> 2;
  int s0 = (blockIdx.x & 3) * 128;
  int tid = threadIdx.x;
  const float* qbase = Qr + (size_t)bd * SPAT + (size_t)s0 * 64;
  for (int i = tid; i < 8192; i += 256) {
    int wsx = i & 63, s = i >> 6;
    QT[wsx][s] = qbase[(size_t)s * 64 + wsx];
  }
  for (int i = tid; i < 2048; i += 256) WL[i >> 5][i & 31] = tab[OFF_W64I + i];
  __syncthreads();
  int sq = tid & 31, fq = tid >> 5;
  float acc[4][4];
  #pragma unroll
  for (int i = 0; i < 4; i++)
    #pragma unroll
    for (int j = 0; j < 4; j++) acc[i][j] = 0.f;
  #pragma unroll 8
  for (int wsx = 0; wsx < 64; wsx++) {
    float4 qv = *reinterpret_cast<const float4*>(&QT[wsx][sq * 4]);
    float4 wv = *reinterpret_cast<const float4*>(&WL[wsx][fq * 4]);
    acc[0][0] += qv.x * wv.x; acc[0][1] += qv.x * wv.y; acc[0][2] += qv.x * wv.z; acc[0][3] += qv.x * wv.w;
    acc[1][0] += qv.y * wv.x; acc[1][1] += qv.y * wv.y; acc[1][2] += qv.y * wv.z; acc[1][3] += qv.y * wv.w;
    acc[2][0] += qv.z * wv.x; acc[2][1] += qv.z * wv.y; acc[2][2] += qv.z * wv.z; acc[2][3] += qv.z * wv.w;
    acc[3][0] += qv.w * wv.x; acc[3][1] += qv.w * wv.y; acc[3][2] += qv.w * wv.z; acc[3][3] += qv.w * wv.w;
  }
  #pragma unroll
  for (int i = 0; i < 4; i++) {
    float4 v = make_float4(acc[i][0], acc[i][1], acc[i][2], acc[i][3]);
    *reinterpret_cast<float4*>(&Fw[((size_t)bd * 512 + s0 + sq * 4 + i) * 32 + fq * 4]) = v;
  }
}

// ---------------- K3a: t-DFT over all kt-hat, IN-PLACE in Fw buffer ----------------
__global__ __launch_bounds__(256) void k3a_tdft(float* __restrict__ FwU, const float* __restrict__ tab) {
  __shared__ float2 W16L[16][16];
  int bd = blockIdx.x;
  int tid = threadIdx.x;
  W16L[tid >> 4][tid & 15] = reinterpret_cast<const float2*>(tab + OFF_W16)[tid];
  __syncthreads();
  float2* base = reinterpret_cast<float2*>(FwU) + (size_t)bd * 8192;
  float2 a0[16], a1[16];
  #pragma unroll
  for (int k = 0; k < 16; k++) { a0[k] = make_float2(0.f, 0.f); a1[k] = make_float2(0.f, 0.f); }
  #pragma unroll
  for (int t = 0; t < 16; t++) {
    float2 v0 = base[t * 512 + tid];
    float2 v1 = base[t * 512 + 256 + tid];
    #pragma unroll
    for (int k = 0; k < 16; k++) {
      float2 w = W16L[t][k];
      a0[k].x += w.x * v0.x - w.y * v0.y; a0[k].y += w.x * v0.y + w.y * v0.x;
      a1[k].x += w.x * v1.x - w.y * v1.y; a1[k].y += w.x * v1.y + w.y * v1.x;
    }
  }
  #pragma unroll
  for (int k = 0; k < 16; k++) {
    base[k * 512 + tid] = a0[k];
    base[k * 512 + 256 + tid] = a1[k];
  }
}

// ---------------- K3s: X[bd][p][f] = sum_hs fh[p][hs] * U[bd][kt[p]][hs][f] ----------------
__global__ __launch_bounds__(1024) void k3s_sel(const float* __restrict__ U, const float* __restrict__ tab,
                                                const int* __restrict__ panel, float* __restrict__ X) {
  __shared__ float2 fhT[32][64];
  __shared__ int ktl[64];
  int bd = blockIdx.x;
  int tid = threadIdx.x;
  for (int i = tid; i < 2048; i += 1024) fhT[i >> 6][i & 63] = reinterpret_cast<const float2*>(tab + OFF_FHT)[i];
  if (tid < 64) ktl[tid] = panel[tid] >> 5;
  __syncthreads();
  int p = tid >> 4, f = tid & 15;
  int kt = ktl[p];
  const float2* ub = reinterpret_cast<const float2*>(U) + (size_t)bd * 8192 + (size_t)kt * 512 + f;
  float ar = 0.f, ai = 0.f;
  #pragma unroll 8
  for (int hs = 0; hs < 32; hs++) {
    float2 e = fhT[hs][p];
    float2 u = ub[hs * 16];
    ar += u.x * e.x - u.y * e.y;
    ai += u.x * e.y + u.y * e.x;
  }
  reinterpret_cast<float2*>(X)[(size_t)bd * 1024 + tid] = make_float2(ar, ai);
}

// ---------------- K3b: mode mix out_sel = sum_i x_sel * w ----------------
__global__ __launch_bounds__(512) void k3b_mix(const float* __restrict__ X, const float* __restrict__ wreal,
                                               const float* __restrict__ wimag, float* __restrict__ V) {
  __shared__ float2 xs[4][32][16];
  int h = blockIdx.x >> 6;
  int p = blockIdx.x & 63;
  int tid = threadIdx.x;
  const float2* Xv = reinterpret_cast<const float2*>(X);
  for (int i = tid; i < 2048; i += 512) {
    int b = i >> 9, ii = (i >> 4) & 31, f = i & 15;
    xs[b][ii][f] = Xv[((size_t)(b * 256 + h * 32 + ii) * MP + p) * ML + f];
  }
  __syncthreads();
  int o = tid >> 4, f = tid & 15;
  float accr[4] = {0, 0, 0, 0}, acci[4] = {0, 0, 0, 0};
  for (int i = 0; i < 32; i++) {
    size_t wofs = ((((size_t)h * 32 + i) * 32 + o) * MP + p) * ML + f;
    float wr = wreal[wofs], wi = wimag[wofs];
    #pragma unroll
    for (int b = 0; b < 4; b++) {
      float2 xv = xs[b][i][f];
      accr[b] += xv.x * wr - xv.y * wi;
      acci[b] += xv.x * wi + xv.y * wr;
    }
  }
  #pragma unroll
  for (int b = 0; b < 4; b++)
    reinterpret_cast<float2*>(V)[((size_t)(b * 256 + h * 32 + o) * MP + p) * ML + f] =
        make_float2(accr[b], acci[b]);
}

// ---------------- K4a: inverse spatial DFT -> G[b][c][s][f] (fp32, global) ----------------
__global__ __launch_bounds__(256) void k4a_inv(const float* __restrict__ V, const float* __restrict__ tab,
                                               float* __restrict__ gbuf) {
  __shared__ float2 vl[64][16];
  __shared__ float2 ft[64][16];
  __shared__ float2 fh[64][32];
  int bd = blockIdx.x;
  int tid = threadIdx.x;
  const float2* Vv = reinterpret_cast<const float2*>(V) + (size_t)bd * MP * ML;
  for (int i = tid; i < 1024; i += 256) {
    vl[i >> 4][i & 15] = Vv[i];
    ft[i >> 4][i & 15] = make_float2(tab[OFF_FTRE + i], tab[OFF_FTIM + i]);
  }
  for (int i = tid; i < 2048; i += 256) fh[i >> 5][i & 31] = make_float2(tab[OFF_FHRE + i], tab[OFF_FHIM + i]);
  __syncthreads();
  float g0[16], g1[16];
  #pragma unroll
  for (int f = 0; f < 16; f++) { g0[f] = 0.f; g1[f] = 0.f; }
  int s0 = tid * 2;
  int t0 = s0 >> 5, hs0 = s0 & 31;
  int t1 = (s0 + 1) >> 5, hs1 = (s0 + 1) & 31;
  for (int p = 0; p < 64; p++) {
    float2 et0 = ft[p][t0], eh0 = fh[p][hs0];
    float2 et1 = ft[p][t1], eh1 = fh[p][hs1];
    float er0 = et0.x * eh0.x - et0.y * eh0.y;
    float ei0 = et0.x * eh0.y + et0.y * eh0.x;
    float er1 = et1.x * eh1.x - et1.y * eh1.y;
    float ei1 = et1.x * eh1.y + et1.y * eh1.x;
    #pragma unroll
    for (int f = 0; f < 16; f++) {
      float2 v = vl[p][f];
      g0[f] += v.x * er0 + v.y * ei0;
      g1[f] += v.x * er1 + v.y * ei1;
    }
  }
  float4* gb = reinterpret_cast<float4*>(gbuf + (size_t)bd * 8192 + (size_t)s0 * 16);
  #pragma unroll
  for (int q = 0; q < 4; q++)
    gb[q] = make_float4(g0[q * 4] * (1.f / 512.f), g0[q * 4 + 1] * (1.f / 512.f),
                        g0[q * 4 + 2] * (1.f / 512.f), g0[q * 4 + 3] * (1.f / 512.f));
  #pragma unroll
  for (int q = 0; q < 4; q++)
    gb[4 + q] = make_float4(g1[q * 4] * (1.f / 512.f), g1[q * 4 + 1] * (1.f / 512.f),
                            g1[q * 4 + 2] * (1.f / 512.f), g1[q * 4 + 3] * (1.f / 512.f));
}

// ---------------- K4b: o[b][sp][c] bf16 = sum_f G[b][c][s][f] * cw[f][ws] ----------------
__global__ __launch_bounds__(256) void k4b_cos(const float* __restrict__ gbuf, const float* __restrict__ tab,
                                               unsigned short* __restrict__ ob) {
  __shared__ float Gs[256][17];
  __shared__ float cwL[16][64];
  int s = blockIdx.x, b = blockIdx.y;
  int tid = threadIdx.x;
  for (int i = tid; i < 4096; i += 256) {
    int c = i >> 4, f = i & 15;
    Gs[c][f] = gbuf[(size_t)(b * 256 + c) * 8192 + s * 16 + f];
  }
  for (int i = tid; i < 1024; i += 256) cwL[i >> 6][i & 63] = tab[OFF_CW + i];
  __syncthreads();
  int c0 = (tid & 63) * 4, wsg = tid >> 6;
  float gv[4][16];
  #pragma unroll
  for (int j = 0; j < 4; j++)
    #pragma unroll
    for (int f = 0; f < 16; f++) gv[j][f] = Gs[c0 + j][f];
  for (int wsi = 0; wsi < 16; wsi++) {
    int wsx = wsg * 16 + wsi;
    float a0 = 0.f, a1 = 0.f, a2 = 0.f, a3 = 0.f;
    #pragma unroll
    for (int f = 0; f < 16; f++) {
      float cwv = cwL[f][wsx];
      a0 += gv[0][f] * cwv; a1 += gv[1][f] * cwv; a2 += gv[2][f] * cwv; a3 += gv[3][f] * cwv;
    }
    ushort4 u;
    u.x = f2bf(a0); u.y = f2bf(a1); u.z = f2bf(a2); u.w = f2bf(a3);
    *reinterpret_cast<ushort4*>(&ob[((size_t)b * SPAT + (size_t)s * 64 + wsx) * 256 + c0]) = u;
  }
}

// ---------------- K5: out = o @ Wo + bo via bf16 MFMA, out fp32 [b][sp][d] ----------------
__global__ __launch_bounds__(256) void k5_mfma(const unsigned short* __restrict__ ob,
                                               const unsigned short* __restrict__ wot,
                                               const float* __restrict__ bo, float* __restrict__ out) {
  __shared__ unsigned short Al[128 * 64];
  __shared__ unsigned short Bl[64 * 64];
  int b = blockIdx.x >> 8, sp0 = (blockIdx.x & 255) << 7, d0 = blockIdx.y << 6;
  int tid = threadIdx.x;
  int lane = tid & 63, w = tid >> 6;
  int l15 = lane & 15, kg = lane >> 4;
  int swz = (l15 & 7) << 4;
  f32x4 acc[2][4];
  #pragma unroll
  for (int mi = 0; mi < 2; mi++)
    #pragma unroll
    for (int ni = 0; ni < 4; ni++) acc[mi][ni] = (f32x4){0.f, 0.f, 0.f, 0.f};
  const char* Abase = (const char*)(ob + ((size_t)b * 32768 + sp0) * 256);
  const char* Bbase = (const char*)(wot + (size_t)d0 * 256);
  for (int k0 = 0; k0 < 256; k0 += 64) {
    #pragma unroll
    for (int it = 0; it < 4; it++) {
      int o = tid * 16 + it * 4096;
      int row = o >> 7, cb = o & 127;
      int scb = cb ^ ((row & 7) << 4);
      gl_lds16(Abase + (size_t)row * 512 + k0 * 2 + scb, (char*)Al + o);
    }
    #pragma unroll
    for (int it = 0; it < 2; it++) {
      int o = tid * 16 + it * 4096;
      int row = o >> 7, cb = o & 127;
      int scb = cb ^ ((row & 7) << 4);
      gl_lds16(Bbase + (size_t)row * 512 + k0 * 2 + scb, (char*)Bl + o);
    }
    __syncthreads();
    #pragma unroll
    for (int ks = 0; ks < 2; ks++) {
      int koff = (ks * 64 + kg * 16) ^ swz;
      short8 af[2], bfr[4];
      #pragma unroll
      for (int mi = 0; mi < 2; mi++)
        af[mi] = *(const short8*)((const char*)Al + (w * 32 + mi * 16 + l15) * 128 + koff);
      #pragma unroll
      for (int ni = 0; ni < 4; ni++)
        bfr[ni] = *(const short8*)((const char*)Bl + (ni * 16 + l15) * 128 + koff);
      #pragma unroll
      for (int mi = 0; mi < 2; mi++)
        #pragma unroll
        for (int ni = 0; ni < 4; ni++)
          acc[mi][ni] = __builtin_amdgcn_mfma_f32_16x16x32_bf16(af[mi], bfr[ni], acc[mi][ni], 0, 0, 0);
    }
    __syncthreads();
  }
  #pragma unroll
  for (int ni = 0; ni < 4; ni++) {
    float bov = bo[d0 + ni * 16 + l15];
    int col = d0 + ni * 16 + l15;
    #pragma unroll
    for (int mi = 0; mi < 2; mi++) {
      f32x4 v = acc[mi][ni];
      size_t mbase = (size_t)b * SPAT + sp0 + w * 32 + mi * 16 + kg * 4;
      #pragma unroll
      for (int j = 0; j < 4; j++) out[(mbase + j) * 256 + col] = v[j] + bov;
    }
  }
}

extern "C" void kernel_launch(void* const* d_in, const int* in_sizes, int n_in,
                              void* d_out, int out_size, void* d_ws, size_t ws_size,
                              hipStream_t stream) {
  const float* x  = (const float*)d_in[0];
  const float* Wq = (const float*)d_in[1];
  const float* bq = (const float*)d_in[2];
  // d_in[3..6] = Wk,bk,Wv,bv -- dead in the reference, skipped
  const float* Wo = (const float*)d_in[7];
  const float* bo = (const float*)d_in[8];
  const float* wr = (const float*)d_in[9];
  const float* wi = (const float*)d_in[10];
  const int* panel = (const int*)d_in[11];
  float* ws = (float*)d_ws;
  float* out = (float*)d_out;

  unsigned short* xb  = (unsigned short*)(ws + OFF_FW);   // bf16, dead after k1 (region reused by Fw/U, then gbuf)
  unsigned short* obb = (unsigned short*)(ws + OFF_QR);   // bf16, written k4b (Qr dead after k2)
  unsigned short* wqt = (unsigned short*)(ws + OFF_WT);
  unsigned short* wot = wqt + 65536;

  hipLaunchKernelGGL(k0_tables, dim3(1), dim3(256), 0, stream, panel, ws);
  hipLaunchKernelGGL(conv_w, dim3(8, 8, 2), dim3(256), 0, stream, Wq, Wo, wqt, wot);
  hipLaunchKernelGGL(conv_x, dim3(16384), dim3(256), 0, stream, x, xb);
  hipLaunchKernelGGL(k1_mfma, dim3(1024, 4), dim3(256), 0, stream, xb, wqt, bq, ws + OFF_QR);
  hipLaunchKernelGGL(k2_wsgemm, dim3(4096), dim3(256), 0, stream, ws + OFF_QR, ws, ws + OFF_FW);
  hipLaunchKernelGGL(k3a_tdft, dim3(1024), dim3(256), 0, stream, ws + OFF_FW, ws);
  hipLaunchKernelGGL(k3s_sel, dim3(1024), dim3(1024), 0, stream, ws + OFF_FW, ws, panel, ws + OFF_X);
  hipLaunchKernelGGL(k3b_mix, dim3(512), dim3(512), 0, stream, ws + OFF_X, wr, wi, ws + OFF_V);
  hipLaunchKernelGGL(k4a_inv, dim3(1024), dim3(256), 0, stream, ws + OFF_V, ws, ws + OFF_FW);
  hipLaunchKernelGGL(k4b_cos, dim3(512, 4), dim3(256), 0, stream, ws + OFF_FW, ws, obb);
  hipLaunchKernelGGL(k5_mfma, dim3(1024, 4), dim3(256), 0, stream, obb, wot, bo, out);
}

// Round 4
// 380.127 us; speedup vs baseline: 4.1931x; 1.2026x over previous
//
#include <hip/hip_runtime.h>
#include <hip/hip_bf16.h>
#include <cmath>

// Problem constants
#define BB 4
#define TT 16
#define HH 32
#define WW 64
#define DD 256
#define NHEAD 8
#define EE 32
#define MP 64      // M_PANEL
#define ML 16      // M_LAST
#define SPAT 32768 // TT*HH*WW
#define S2D 512    // TT*HH

// d_ws layout (float offsets)
constexpr size_t OFF_FTRE = 0;        // [p][t] 64x16
constexpr size_t OFF_FTIM = 1024;
constexpr size_t OFF_FHRE = 2048;     // [p][hs] 64x32
constexpr size_t OFF_FHIM = 4096;
constexpr size_t OFF_CW   = 6144;     // [f][ws] 16x64
constexpr size_t OFF_W64I = 7168;     // [ws][f2] 64x32 interleaved re,im
constexpr size_t OFF_W16  = 9216;     // [t][kt] float2 16x16
constexpr size_t OFF_FHT  = 9728;     // [hs][p] float2 32x64
constexpr size_t OFF_XB   = 16384;                 // xb bf16 (16.8M fl slots); after k1f reused: gbuf fp32 (8.4M) + ob bf16 (8.4M fl slots)
constexpr size_t OFF_FW   = OFF_XB + 16777216;     // Fw fp32 [b][s][d][f2] 16.8M floats
constexpr size_t OFF_X    = OFF_FW + 16777216;     // [bd][p][f] cplx 2.1M floats
constexpr size_t OFF_V    = OFF_X + 2097152;       // [bd][p][f] cplx 2.1M floats
constexpr size_t OFF_WT   = OFF_V + 2097152;       // WqT bf16 65536 + WoT bf16 65536

typedef short short8 __attribute__((ext_vector_type(8)));
typedef float f32x4 __attribute__((ext_vector_type(4)));

static __device__ __forceinline__ unsigned short f2bf(float x) {
  union { float f; unsigned u; } v; v.f = x;
  unsigned r = v.u + 0x7fffu + ((v.u >> 16) & 1u);
  return (unsigned short)(r >> 16);
}

static __device__ __forceinline__ void gl_lds16(const void* g, void* l) {
  __builtin_amdgcn_global_load_lds((const __attribute__((address_space(1))) void*)g,
                                   (__attribute__((address_space(3))) void*)l, 16, 0, 0);
}

// ---------------- K0: twiddle tables ----------------
__global__ __launch_bounds__(256) void k0_tables(const int* __restrict__ panel, float* __restrict__ tab) {
  __shared__ int kt[MP], kh[MP];
  int tid = threadIdx.x;
  if (tid < MP) { int s = panel[tid]; kt[tid] = s >> 5; kh[tid] = s & 31; }
  __syncthreads();
  const double PI2 = 6.283185307179586476925286766559;
  for (int i = tid; i < 1024; i += 256) {  // FT [p][t]
    int p = i >> 4, t = i & 15;
    double a = -PI2 * (double)((t * kt[p]) & 15) / 16.0;
    tab[OFF_FTRE + i] = (float)cos(a);
    tab[OFF_FTIM + i] = (float)sin(a);
  }
  for (int i = tid; i < 2048; i += 256) {  // FH [p][hs]
    int p = i >> 5, hs = i & 31;
    double a = -PI2 * (double)((hs * kh[p]) & 31) / 32.0;
    tab[OFF_FHRE + i] = (float)cos(a);
    tab[OFF_FHIM + i] = (float)sin(a);
  }
  for (int i = tid; i < 1024; i += 256) {  // CW [f][ws]
    int f = i >> 6, wsx = i & 63;
    double a = PI2 * (double)((f * wsx) & 63) / 64.0;
    tab[OFF_CW + i] = (f == 0) ? (1.0f / 64.0f) : (float)(2.0 * cos(a) / 64.0);
  }
  for (int i = tid; i < 2048; i += 256) {  // W64I [ws][f2]
    int wsx = i >> 5, f2 = i & 31; int f = f2 >> 1;
    double a = -PI2 * (double)((wsx * f) & 63) / 64.0;
    tab[OFF_W64I + i] = (f2 & 1) ? (float)sin(a) : (float)cos(a);
  }
  if (tid < 256) {                         // W16 [t][kt] float2
    int t = tid >> 4, k = tid & 15;
    double a = -PI2 * (double)((t * k) & 15) / 16.0;
    tab[OFF_W16 + 2 * tid]     = (float)cos(a);
    tab[OFF_W16 + 2 * tid + 1] = (float)sin(a);
  }
  for (int i = tid; i < 2048; i += 256) {  // FHT [hs][p] float2
    int hs = i >> 6, p = i & 63;
    double a = -PI2 * (double)((hs * kh[p]) & 31) / 32.0;
    tab[OFF_FHT + 2 * i]     = (float)cos(a);
    tab[OFF_FHT + 2 * i + 1] = (float)sin(a);
  }
}

// ---------------- conv_x: x fp32 -> xb bf16 ----------------
__global__ __launch_bounds__(256) void conv_x(const float* __restrict__ x, unsigned short* __restrict__ xb) {
  size_t i0 = ((size_t)blockIdx.x * 256 + threadIdx.x) * 8;
  float4 a = *reinterpret_cast<const float4*>(x + i0);
  float4 b = *reinterpret_cast<const float4*>(x + i0 + 4);
  short8 v;
  v[0] = (short)f2bf(a.x); v[1] = (short)f2bf(a.y); v[2] = (short)f2bf(a.z); v[3] = (short)f2bf(a.w);
  v[4] = (short)f2bf(b.x); v[5] = (short)f2bf(b.y); v[6] = (short)f2bf(b.z); v[7] = (short)f2bf(b.w);
  *reinterpret_cast<short8*>(xb + i0) = v;
}

// ---------------- conv_w: Wq/Wo fp32 [k][d] -> WT bf16 [d][k] ----------------
__global__ __launch_bounds__(256) void conv_w(const float* __restrict__ Wq, const float* __restrict__ Wo,
                                              unsigned short* __restrict__ wqt, unsigned short* __restrict__ wot) {
  __shared__ float tile[32][33];
  const float* src = blockIdx.z ? Wo : Wq;
  unsigned short* dst = blockIdx.z ? wot : wqt;
  int k0 = blockIdx.x * 32, d0 = blockIdx.y * 32;
  int tx = threadIdx.x & 31, r4 = threadIdx.x >> 5;
  #pragma unroll
  for (int it = 0; it < 4; it++) {
    int row = r4 + it * 8;
    tile[row][tx] = src[(size_t)(k0 + row) * 256 + d0 + tx];
  }
  __syncthreads();
  #pragma unroll
  for (int it = 0; it < 4; it++) {
    int row = r4 + it * 8;
    dst[(size_t)(d0 + row) * 256 + k0 + tx] = f2bf(tile[tx][row]);
  }
}

// ---------------- K1f: Q = x @ Wq + bq (bf16 MFMA) fused with ws-DFT -> Fw[b][s][d][f2] ----------------
__global__ __launch_bounds__(256) void k1f(const unsigned short* __restrict__ xb,
                                           const unsigned short* __restrict__ wqt,
                                           const float* __restrict__ bq, const float* __restrict__ tab,
                                           float* __restrict__ Fwg) {
  __shared__ char smem[59904];
  unsigned short* Al = (unsigned short*)smem;            // 16384 B staging (phase 1)
  unsigned short* Bl = (unsigned short*)(smem + 16384);  // 8192 B  staging (phase 1)
  float* QL  = (float*)smem;                             // [128][65] fp32 = 33280 B (phase 2, overlays Al/Bl)
  float* FwL = (float*)(smem + 33280);                   // [2][64][36] fp32 = 18432 B (phase 2)
  float* WL  = (float*)(smem + 51712);                   // [64][32] fp32 = 8192 B (persistent)
  int b = blockIdx.x >> 8, sp0 = (blockIdx.x & 255) << 7, d0 = blockIdx.y << 6;
  int tid = threadIdx.x;
  int lane = tid & 63, w = tid >> 6;
  int l15 = lane & 15, kg = lane >> 4;
  int swz = (l15 & 7) << 4;
  // persistent DFT table load (region disjoint from staging)
  for (int i = tid; i < 2048; i += 256) WL[i] = tab[OFF_W64I + i];
  f32x4 acc[2][4];
  #pragma unroll
  for (int mi = 0; mi < 2; mi++)
    #pragma unroll
    for (int ni = 0; ni < 4; ni++) acc[mi][ni] = (f32x4){0.f, 0.f, 0.f, 0.f};
  const char* Abase = (const char*)(xb + ((size_t)b * 32768 + sp0) * 256);
  const char* Bbase = (const char*)(wqt + (size_t)d0 * 256);
  for (int k0 = 0; k0 < 256; k0 += 64) {
    #pragma unroll
    for (int it = 0; it < 4; it++) {
      int o = tid * 16 + it * 4096;
      int row = o >> 7, cb = o & 127;
      int scb = cb ^ ((row & 7) << 4);
      gl_lds16(Abase + (size_t)row * 512 + k0 * 2 + scb, (char*)Al + o);
    }
    #pragma unroll
    for (int it = 0; it < 2; it++) {
      int o = tid * 16 + it * 4096;
      int row = o >> 7, cb = o & 127;
      int scb = cb ^ ((row & 7) << 4);
      gl_lds16(Bbase + (size_t)row * 512 + k0 * 2 + scb, (char*)Bl + o);
    }
    __syncthreads();
    #pragma unroll
    for (int ks = 0; ks < 2; ks++) {
      int koff = (ks * 64 + kg * 16) ^ swz;
      short8 af[2], bfr[4];
      #pragma unroll
      for (int mi = 0; mi < 2; mi++)
        af[mi] = *(const short8*)((const char*)Al + (w * 32 + mi * 16 + l15) * 128 + koff);
      #pragma unroll
      for (int ni = 0; ni < 4; ni++)
        bfr[ni] = *(const short8*)((const char*)Bl + (ni * 16 + l15) * 128 + koff);
      #pragma unroll
      for (int mi = 0; mi < 2; mi++)
        #pragma unroll
        for (int ni = 0; ni < 4; ni++)
          acc[mi][ni] = __builtin_amdgcn_mfma_f32_16x16x32_bf16(af[mi], bfr[ni], acc[mi][ni], 0, 0, 0);
    }
    __syncthreads();
  }
  // phase 2a: Q (+bias) -> QL
  #pragma unroll
  for (int ni = 0; ni < 4; ni++) {
    float bqv = bq[d0 + ni * 16 + l15];
    #pragma unroll
    for (int mi = 0; mi < 2; mi++) {
      f32x4 vv = acc[mi][ni];
      int m = w * 32 + mi * 16 + kg * 4;
      #pragma unroll
      for (int j = 0; j < 4; j++)
        QL[(m + j) * 65 + ni * 16 + l15] = vv[j] + bqv;
    }
  }
  __syncthreads();
  // phase 2b: ws-DFT: thread = (s, d, f2-half)
  {
    int s = tid >> 7, dd = (tid >> 1) & 63, f2p = tid & 1;
    float acc2[16];
    #pragma unroll
    for (int k = 0; k < 16; k++) acc2[k] = 0.f;
    const float* qrow = &QL[(s * 64) * 65 + dd];
    const float* wbase = &WL[f2p * 16];
    #pragma unroll 4
    for (int wsx = 0; wsx < 64; wsx++) {
      float q = qrow[wsx * 65];
      const float* wrow = wbase + wsx * 32;
      #pragma unroll
      for (int k = 0; k < 16; k++) acc2[k] += q * wrow[k];
    }
    float* fo = &FwL[(s * 64 + dd) * 36 + f2p * 16];
    #pragma unroll
    for (int k4 = 0; k4 < 4; k4++)
      *reinterpret_cast<float4*>(fo + k4 * 4) =
          make_float4(acc2[k4 * 4], acc2[k4 * 4 + 1], acc2[k4 * 4 + 2], acc2[k4 * 4 + 3]);
  }
  __syncthreads();
  // phase 2c: FwL -> global Fw[b][s][256d][32f2], coalesced
  {
    int s0 = (blockIdx.x & 255) << 1;
    for (int i = tid; i < 1024; i += 256) {
      int s = i >> 9, rem = i & 511, dd = rem >> 3, f4 = rem & 7;
      float4 val = *reinterpret_cast<const float4*>(&FwL[(s * 64 + dd) * 36 + f4 * 4]);
      size_t gidx = ((size_t)(b * 512 + s0 + s) * 256 + d0 + dd) * 32 + f4 * 4;
      *reinterpret_cast<float4*>(&Fwg[gidx]) = val;
    }
  }
}

// ---------------- K3f: per (b,d): t-DFT (in-place LDS) + selected hs-reduction -> X[bd][p][f] ----------------
__global__ __launch_bounds__(512) void k3f(const float* __restrict__ Fwg, const float* __restrict__ tab,
                                           const int* __restrict__ panel, float* __restrict__ X) {
  __shared__ float2 Floc[8192];   // 64 KB: [s=512][f=16] then in-place [kt=16][hs=32][f=16]
  __shared__ float2 fhT[32][64];  // 16 KB
  __shared__ float2 W16L[16][16]; // 2 KB
  __shared__ int ktl[64];
  int bd = blockIdx.x; int b = bd >> 8; int d = bd & 255;
  int tid = threadIdx.x;
  if (tid < 256) W16L[tid >> 4][tid & 15] = reinterpret_cast<const float2*>(tab + OFF_W16)[tid];
  for (int i = tid; i < 2048; i += 512) fhT[i >> 6][i & 63] = reinterpret_cast<const float2*>(tab + OFF_FHT)[i];
  if (tid < 64) ktl[tid] = panel[tid] >> 5;
  // stage this (b,d) column of Fw: 512 rows x 128 B, scattered global -> linear LDS
  {
    const char* gb = (const char*)Fwg;
    #pragma unroll
    for (int r = 0; r < 8; r++) {
      int o = r * 8192 + tid * 16;
      int s = o >> 7; int c16 = (o >> 4) & 7;
      size_t gaddr = ((size_t)(b * 512 + s) * 256 + d) * 128 + (size_t)c16 * 16;
      gl_lds16(gb + gaddr, (char*)Floc + o);
    }
  }
  __syncthreads();
  // t-phase: thread owns column (hs, f); in-place safe (column-private)
  int hs = tid >> 4, f = tid & 15;
  float2 v[16];
  #pragma unroll
  for (int t = 0; t < 16; t++) v[t] = Floc[(t * 32 + hs) * 16 + f];
  float2 a[16];
  #pragma unroll
  for (int k = 0; k < 16; k++) a[k] = make_float2(0.f, 0.f);
  #pragma unroll
  for (int t = 0; t < 16; t++) {
    float2 vv = v[t];
    #pragma unroll
    for (int k = 0; k < 16; k++) {
      float2 w = W16L[t][k];
      a[k].x += w.x * vv.x - w.y * vv.y;
      a[k].y += w.x * vv.y + w.y * vv.x;
    }
  }
  #pragma unroll
  for (int k = 0; k < 16; k++) Floc[(k * 32 + hs) * 16 + f] = a[k];
  __syncthreads();
  // hs-phase: thread handles p = p2 and p2+32 for its f
  int p2 = tid >> 4;
  float2 res[2];
  #pragma unroll
  for (int half = 0; half < 2; half++) {
    int p = p2 + half * 32;
    int kt = ktl[p];
    float ar = 0.f, ai = 0.f;
    #pragma unroll 8
    for (int h = 0; h < 32; h++) {
      float2 e = fhT[h][p];
      float2 u = Floc[(kt * 32 + h) * 16 + f];
      ar += u.x * e.x - u.y * e.y;
      ai += u.x * e.y + u.y * e.x;
    }
    res[half] = make_float2(ar, ai);
  }
  float2* Xo = reinterpret_cast<float2*>(X) + (size_t)bd * 1024;
  Xo[p2 * 16 + f] = res[0];
  Xo[(p2 + 32) * 16 + f] = res[1];
}

// ---------------- K3b: mode mix out_sel = sum_i x_sel * w ----------------
__global__ __launch_bounds__(512) void k3b_mix(const float* __restrict__ X, const float* __restrict__ wreal,
                                               const float* __restrict__ wimag, float* __restrict__ V) {
  __shared__ float2 xs[4][32][16];
  int h = blockIdx.x >> 6;
  int p = blockIdx.x & 63;
  int tid = threadIdx.x;
  const float2* Xv = reinterpret_cast<const float2*>(X);
  for (int i = tid; i < 2048; i += 512) {
    int b = i >> 9, ii = (i >> 4) & 31, f = i & 15;
    xs[b][ii][f] = Xv[((size_t)(b * 256 + h * 32 + ii) * MP + p) * ML + f];
  }
  __syncthreads();
  int o = tid >> 4, f = tid & 15;
  float accr[4] = {0, 0, 0, 0}, acci[4] = {0, 0, 0, 0};
  for (int i = 0; i < 32; i++) {
    size_t wofs = ((((size_t)h * 32 + i) * 32 + o) * MP + p) * ML + f;
    float wr = wreal[wofs], wi = wimag[wofs];
    #pragma unroll
    for (int b = 0; b < 4; b++) {
      float2 xv = xs[b][i][f];
      accr[b] += xv.x * wr - xv.y * wi;
      acci[b] += xv.x * wi + xv.y * wr;
    }
  }
  #pragma unroll
  for (int b = 0; b < 4; b++)
    reinterpret_cast<float2*>(V)[((size_t)(b * 256 + h * 32 + o) * MP + p) * ML + f] =
        make_float2(accr[b], acci[b]);
}

// ---------------- K4a: inverse spatial DFT -> G[b][c][s][f] (fp32, global) ----------------
__global__ __launch_bounds__(256) void k4a_inv(const float* __restrict__ V, const float* __restrict__ tab,
                                               float* __restrict__ gbuf) {
  __shared__ float2 vl[64][16];
  __shared__ float2 ft[64][16];
  __shared__ float2 fh[64][32];
  int bd = blockIdx.x;
  int tid = threadIdx.x;
  const float2* Vv = reinterpret_cast<const float2*>(V) + (size_t)bd * MP * ML;
  for (int i = tid; i < 1024; i += 256) {
    vl[i >> 4][i & 15] = Vv[i];
    ft[i >> 4][i & 15] = make_float2(tab[OFF_FTRE + i], tab[OFF_FTIM + i]);
  }
  for (int i = tid; i < 2048; i += 256) fh[i >> 5][i & 31] = make_float2(tab[OFF_FHRE + i], tab[OFF_FHIM + i]);
  __syncthreads();
  float g0[16], g1[16];
  #pragma unroll
  for (int f = 0; f < 16; f++) { g0[f] = 0.f; g1[f] = 0.f; }
  int s0 = tid * 2;
  int t0 = s0 >> 5, hs0 = s0 & 31;
  int t1 = (s0 + 1) >> 5, hs1 = (s0 + 1) & 31;
  for (int p = 0; p < 64; p++) {
    float2 et0 = ft[p][t0], eh0 = fh[p][hs0];
    float2 et1 = ft[p][t1], eh1 = fh[p][hs1];
    float er0 = et0.x * eh0.x - et0.y * eh0.y;
    float ei0 = et0.x * eh0.y + et0.y * eh0.x;
    float er1 = et1.x * eh1.x - et1.y * eh1.y;
    float ei1 = et1.x * eh1.y + et1.y * eh1.x;
    #pragma unroll
    for (int f = 0; f < 16; f++) {
      float2 v = vl[p][f];
      g0[f] += v.x * er0 + v.y * ei0;
      g1[f] += v.x * er1 + v.y * ei1;
    }
  }
  float4* gb = reinterpret_cast<float4*>(gbuf + (size_t)bd * 8192 + (size_t)s0 * 16);
  #pragma unroll
  for (int q = 0; q < 4; q++)
    gb[q] = make_float4(g0[q * 4] * (1.f / 512.f), g0[q * 4 + 1] * (1.f / 512.f),
                        g0[q * 4 + 2] * (1.f / 512.f), g0[q * 4 + 3] * (1.f / 512.f));
  #pragma unroll
  for (int q = 0; q < 4; q++)
    gb[4 + q] = make_float4(g1[q * 4] * (1.f / 512.f), g1[q * 4 + 1] * (1.f / 512.f),
                            g1[q * 4 + 2] * (1.f / 512.f), g1[q * 4 + 3] * (1.f / 512.f));
}

// ---------------- K4b: o[b][sp][c] bf16 = sum_f G[b][c][s][f] * cw[f][ws] ----------------
__global__ __launch_bounds__(256) void k4b_cos(const float* __restrict__ gbuf, const float* __restrict__ tab,
                                               unsigned short* __restrict__ ob) {
  __shared__ float Gs[256][17];
  __shared__ float cwL[16][64];
  int s = blockIdx.x, b = blockIdx.y;
  int tid = threadIdx.x;
  for (int i = tid; i < 4096; i += 256) {
    int c = i >> 4, f = i & 15;
    Gs[c][f] = gbuf[(size_t)(b * 256 + c) * 8192 + s * 16 + f];
  }
  for (int i = tid; i < 1024; i += 256) cwL[i >> 6][i & 63] = tab[OFF_CW + i];
  __syncthreads();
  int c0 = (tid & 63) * 4, wsg = tid >> 6;
  float gv[4][16];
  #pragma unroll
  for (int j = 0; j < 4; j++)
    #pragma unroll
    for (int f = 0; f < 16; f++) gv[j][f] = Gs[c0 + j][f];
  for (int wsi = 0; wsi < 16; wsi++) {
    int wsx = wsg * 16 + wsi;
    float a0 = 0.f, a1 = 0.f, a2 = 0.f, a3 = 0.f;
    #pragma unroll
    for (int f = 0; f < 16; f++) {
      float cwv = cwL[f][wsx];
      a0 += gv[0][f] * cwv; a1 += gv[1][f] * cwv; a2 += gv[2][f] * cwv; a3 += gv[3][f] * cwv;
    }
    ushort4 u;
    u.x = f2bf(a0); u.y = f2bf(a1); u.z = f2bf(a2); u.w = f2bf(a3);
    *reinterpret_cast<ushort4*>(&ob[((size_t)b * SPAT + (size_t)s * 64 + wsx) * 256 + c0]) = u;
  }
}

// ---------------- K5: out = o @ Wo + bo via bf16 MFMA, out fp32 [b][sp][d] ----------------
__global__ __launch_bounds__(256) void k5_mfma(const unsigned short* __restrict__ ob,
                                               const unsigned short* __restrict__ wot,
                                               const float* __restrict__ bo, float* __restrict__ out) {
  __shared__ unsigned short Al[128 * 64];
  __shared__ unsigned short Bl[64 * 64];
  int b = blockIdx.x >> 8, sp0 = (blockIdx.x & 255) << 7, d0 = blockIdx.y << 6;
  int tid = threadIdx.x;
  int lane = tid & 63, w = tid >> 6;
  int l15 = lane & 15, kg = lane >> 4;
  int swz = (l15 & 7) << 4;
  f32x4 acc[2][4];
  #pragma unroll
  for (int mi = 0; mi < 2; mi++)
    #pragma unroll
    for (int ni = 0; ni < 4; ni++) acc[mi][ni] = (f32x4){0.f, 0.f, 0.f, 0.f};
  const char* Abase = (const char*)(ob + ((size_t)b * 32768 + sp0) * 256);
  const char* Bbase = (const char*)(wot + (size_t)d0 * 256);
  for (int k0 = 0; k0 < 256; k0 += 64) {
    #pragma unroll
    for (int it = 0; it < 4; it++) {
      int o = tid * 16 + it * 4096;
      int row = o >> 7, cb = o & 127;
      int scb = cb ^ ((row & 7) << 4);
      gl_lds16(Abase + (size_t)row * 512 + k0 * 2 + scb, (char*)Al + o);
    }
    #pragma unroll
    for (int it = 0; it < 2; it++) {
      int o = tid * 16 + it * 4096;
      int row = o >> 7, cb = o & 127;
      int scb = cb ^ ((row & 7) << 4);
      gl_lds16(Bbase + (size_t)row * 512 + k0 * 2 + scb, (char*)Bl + o);
    }
    __syncthreads();
    #pragma unroll
    for (int ks = 0; ks < 2; ks++) {
      int koff = (ks * 64 + kg * 16) ^ swz;
      short8 af[2], bfr[4];
      #pragma unroll
      for (int mi = 0; mi < 2; mi++)
        af[mi] = *(const short8*)((const char*)Al + (w * 32 + mi * 16 + l15) * 128 + koff);
      #pragma unroll
      for (int ni = 0; ni < 4; ni++)
        bfr[ni] = *(const short8*)((const char*)Bl + (ni * 16 + l15) * 128 + koff);
      #pragma unroll
      for (int mi = 0; mi < 2; mi++)
        #pragma unroll
        for (int ni = 0; ni < 4; ni++)
          acc[mi][ni] = __builtin_amdgcn_mfma_f32_16x16x32_bf16(af[mi], bfr[ni], acc[mi][ni], 0, 0, 0);
    }
    __syncthreads();
  }
  #pragma unroll
  for (int ni = 0; ni < 4; ni++) {
    float bov = bo[d0 + ni * 16 + l15];
    int col = d0 + ni * 16 + l15;
    #pragma unroll
    for (int mi = 0; mi < 2; mi++) {
      f32x4 v = acc[mi][ni];
      size_t mbase = (size_t)b * SPAT + sp0 + w * 32 + mi * 16 + kg * 4;
      #pragma unroll
      for (int j = 0; j < 4; j++) out[(mbase + j) * 256 + col] = v[j] + bov;
    }
  }
}

extern "C" void kernel_launch(void* const* d_in, const int* in_sizes, int n_in,
                              void* d_out, int out_size, void* d_ws, size_t ws_size,
                              hipStream_t stream) {
  const float* x  = (const float*)d_in[0];
  const float* Wq = (const float*)d_in[1];
  const float* bq = (const float*)d_in[2];
  // d_in[3..6] = Wk,bk,Wv,bv -- dead in the reference, skipped
  const float* Wo = (const float*)d_in[7];
  const float* bo = (const float*)d_in[8];
  const float* wr = (const float*)d_in[9];
  const float* wi = (const float*)d_in[10];
  const int* panel = (const int*)d_in[11];
  float* ws = (float*)d_ws;
  float* out = (float*)d_out;

  unsigned short* xb   = (unsigned short*)(ws + OFF_XB);             // dead after k1f
  float*          gbuf = ws + OFF_XB;                                // reuses xb region (k4a onward)
  unsigned short* obb  = (unsigned short*)(ws + OFF_XB + 8388608);   // reuses xb region 2nd half
  unsigned short* wqt  = (unsigned short*)(ws + OFF_WT);
  unsigned short* wot  = wqt + 65536;

  hipLaunchKernelGGL(k0_tables, dim3(1), dim3(256), 0, stream, panel, ws);
  hipLaunchKernelGGL(conv_w, dim3(8, 8, 2), dim3(256), 0, stream, Wq, Wo, wqt, wot);
  hipLaunchKernelGGL(conv_x, dim3(16384), dim3(256), 0, stream, x, xb);
  hipLaunchKernelGGL(k1f, dim3(1024, 4), dim3(256), 0, stream, xb, wqt, bq, ws, ws + OFF_FW);
  hipLaunchKernelGGL(k3f, dim3(1024), dim3(512), 0, stream, ws + OFF_FW, ws, panel, ws + OFF_X);
  hipLaunchKernelGGL(k3b_mix, dim3(512), dim3(512), 0, stream, ws + OFF_X, wr, wi, ws + OFF_V);
  hipLaunchKernelGGL(k4a_inv, dim3(1024), dim3(256), 0, stream, ws + OFF_V, ws, gbuf);
  hipLaunchKernelGGL(k4b_cos, dim3(512, 4), dim3(256), 0, stream, gbuf, ws, obb);
  hipLaunchKernelGGL(k5_mfma, dim3(1024, 4), dim3(256), 0, stream, obb, wot, bo, out);
}

// Round 5
// 360.964 us; speedup vs baseline: 4.4158x; 1.0531x over previous
//
#include <hip/hip_runtime.h>
#include <hip/hip_bf16.h>
#include <cmath>

// Problem constants
#define BB 4
#define TT 16
#define HH 32
#define WW 64
#define DD 256
#define NHEAD 8
#define EE 32
#define MP 64      // M_PANEL
#define ML 16      // M_LAST
#define SPAT 32768 // TT*HH*WW
#define S2D 512    // TT*HH

// d_ws layout (float offsets)
constexpr size_t OFF_FTRE = 0;        // [p][t] 64x16
constexpr size_t OFF_FTIM = 1024;
constexpr size_t OFF_FHRE = 2048;     // [p][hs] 64x32
constexpr size_t OFF_FHIM = 4096;
constexpr size_t OFF_CW   = 6144;     // [f][ws] 16x64
constexpr size_t OFF_W64I = 7168;     // [ws][f2] 64x32 interleaved re,im
constexpr size_t OFF_W16  = 9216;     // [t][kt] float2 16x16
constexpr size_t OFF_FHT  = 9728;     // [hs][p] float2 32x64
constexpr size_t OFF_XB   = 16384;                 // xb bf16 (16.8M fl slots); after k1f reused: gbuf fp32 (8.4M) + ob bf16 (8.4M fl slots)
constexpr size_t OFF_FW   = OFF_XB + 16777216;     // Fw fp32 [b][s][d][f2] 16.8M floats
constexpr size_t OFF_X    = OFF_FW + 16777216;     // [bd][p][f] cplx 2.1M floats
constexpr size_t OFF_V    = OFF_X + 2097152;       // [bd][p][f] cplx 2.1M floats
constexpr size_t OFF_WT   = OFF_V + 2097152;       // WqT bf16 65536 + WoT bf16 65536

typedef short short8 __attribute__((ext_vector_type(8)));
typedef float f32x4 __attribute__((ext_vector_type(4)));

static __device__ __forceinline__ unsigned short f2bf(float x) {
  union { float f; unsigned u; } v; v.f = x;
  unsigned r = v.u + 0x7fffu + ((v.u >> 16) & 1u);
  return (unsigned short)(r >> 16);
}

static __device__ __forceinline__ void gl_lds16(const void* g, void* l) {
  __builtin_amdgcn_global_load_lds((const __attribute__((address_space(1))) void*)g,
                                   (__attribute__((address_space(3))) void*)l, 16, 0, 0);
}

// ---------------- K0: twiddle tables ----------------
__global__ __launch_bounds__(256) void k0_tables(const int* __restrict__ panel, float* __restrict__ tab) {
  __shared__ int kt[MP], kh[MP];
  int tid = threadIdx.x;
  if (tid < MP) { int s = panel[tid]; kt[tid] = s >> 5; kh[tid] = s & 31; }
  __syncthreads();
  const double PI2 = 6.283185307179586476925286766559;
  for (int i = tid; i < 1024; i += 256) {  // FT [p][t]
    int p = i >> 4, t = i & 15;
    double a = -PI2 * (double)((t * kt[p]) & 15) / 16.0;
    tab[OFF_FTRE + i] = (float)cos(a);
    tab[OFF_FTIM + i] = (float)sin(a);
  }
  for (int i = tid; i < 2048; i += 256) {  // FH [p][hs]
    int p = i >> 5, hs = i & 31;
    double a = -PI2 * (double)((hs * kh[p]) & 31) / 32.0;
    tab[OFF_FHRE + i] = (float)cos(a);
    tab[OFF_FHIM + i] = (float)sin(a);
  }
  for (int i = tid; i < 1024; i += 256) {  // CW [f][ws]
    int f = i >> 6, wsx = i & 63;
    double a = PI2 * (double)((f * wsx) & 63) / 64.0;
    tab[OFF_CW + i] = (f == 0) ? (1.0f / 64.0f) : (float)(2.0 * cos(a) / 64.0);
  }
  for (int i = tid; i < 2048; i += 256) {  // W64I [ws][f2]
    int wsx = i >> 5, f2 = i & 31; int f = f2 >> 1;
    double a = -PI2 * (double)((wsx * f) & 63) / 64.0;
    tab[OFF_W64I + i] = (f2 & 1) ? (float)sin(a) : (float)cos(a);
  }
  if (tid < 256) {                         // W16 [t][kt] float2
    int t = tid >> 4, k = tid & 15;
    double a = -PI2 * (double)((t * k) & 15) / 16.0;
    tab[OFF_W16 + 2 * tid]     = (float)cos(a);
    tab[OFF_W16 + 2 * tid + 1] = (float)sin(a);
  }
  for (int i = tid; i < 2048; i += 256) {  // FHT [hs][p] float2
    int hs = i >> 6, p = i & 63;
    double a = -PI2 * (double)((hs * kh[p]) & 31) / 32.0;
    tab[OFF_FHT + 2 * i]     = (float)cos(a);
    tab[OFF_FHT + 2 * i + 1] = (float)sin(a);
  }
}

// ---------------- conv_x: x fp32 -> xb bf16 ----------------
__global__ __launch_bounds__(256) void conv_x(const float* __restrict__ x, unsigned short* __restrict__ xb) {
  size_t i0 = ((size_t)blockIdx.x * 256 + threadIdx.x) * 8;
  float4 a = *reinterpret_cast<const float4*>(x + i0);
  float4 b = *reinterpret_cast<const float4*>(x + i0 + 4);
  short8 v;
  v[0] = (short)f2bf(a.x); v[1] = (short)f2bf(a.y); v[2] = (short)f2bf(a.z); v[3] = (short)f2bf(a.w);
  v[4] = (short)f2bf(b.x); v[5] = (short)f2bf(b.y); v[6] = (short)f2bf(b.z); v[7] = (short)f2bf(b.w);
  *reinterpret_cast<short8*>(xb + i0) = v;
}

// ---------------- conv_w: Wq/Wo fp32 [k][d] -> WT bf16 [d][k] ----------------
__global__ __launch_bounds__(256) void conv_w(const float* __restrict__ Wq, const float* __restrict__ Wo,
                                              unsigned short* __restrict__ wqt, unsigned short* __restrict__ wot) {
  __shared__ float tile[32][33];
  const float* src = blockIdx.z ? Wo : Wq;
  unsigned short* dst = blockIdx.z ? wot : wqt;
  int k0 = blockIdx.x * 32, d0 = blockIdx.y * 32;
  int tx = threadIdx.x & 31, r4 = threadIdx.x >> 5;
  #pragma unroll
  for (int it = 0; it < 4; it++) {
    int row = r4 + it * 8;
    tile[row][tx] = src[(size_t)(k0 + row) * 256 + d0 + tx];
  }
  __syncthreads();
  #pragma unroll
  for (int it = 0; it < 4; it++) {
    int row = r4 + it * 8;
    dst[(size_t)(d0 + row) * 256 + k0 + tx] = f2bf(tile[tx][row]);
  }
}

// ---------------- K1f: Q = x @ Wq + bq (bf16 MFMA) fused with ws-DFT -> Fw[b][s][d][f2] ----------------
__global__ __launch_bounds__(256) void k1f(const unsigned short* __restrict__ xb,
                                           const unsigned short* __restrict__ wqt,
                                           const float* __restrict__ bq, const float* __restrict__ tab,
                                           float* __restrict__ Fwg) {
  __shared__ char smem[43008];
  unsigned short* Al = (unsigned short*)smem;            // 16384 B staging (phase 1)
  unsigned short* Bl = (unsigned short*)(smem + 16384);  // 8192 B  staging (phase 1)
  float* QL  = (float*)smem;                             // [128][68] fp32 = 34816 B (phase 2, overlays Al/Bl)
  float* WL  = (float*)(smem + 34816);                   // [64][32] fp32 = 8192 B (persistent)
  int b = blockIdx.x >> 8, sp0 = (blockIdx.x & 255) << 7, d0 = blockIdx.y << 6;
  int tid = threadIdx.x;
  int lane = tid & 63, w = tid >> 6;
  int l15 = lane & 15, kg = lane >> 4;
  int swz = (l15 & 7) << 4;
  // persistent DFT table load (region disjoint from staging)
  for (int i = tid; i < 2048; i += 256) WL[i] = tab[OFF_W64I + i];
  f32x4 acc[2][4];
  #pragma unroll
  for (int mi = 0; mi < 2; mi++)
    #pragma unroll
    for (int ni = 0; ni < 4; ni++) acc[mi][ni] = (f32x4){0.f, 0.f, 0.f, 0.f};
  const char* Abase = (const char*)(xb + ((size_t)b * 32768 + sp0) * 256);
  const char* Bbase = (const char*)(wqt + (size_t)d0 * 256);
  for (int k0 = 0; k0 < 256; k0 += 64) {
    #pragma unroll
    for (int it = 0; it < 4; it++) {
      int o = tid * 16 + it * 4096;
      int row = o >> 7, cb = o & 127;
      int scb = cb ^ ((row & 7) << 4);
      gl_lds16(Abase + (size_t)row * 512 + k0 * 2 + scb, (char*)Al + o);
    }
    #pragma unroll
    for (int it = 0; it < 2; it++) {
      int o = tid * 16 + it * 4096;
      int row = o >> 7, cb = o & 127;
      int scb = cb ^ ((row & 7) << 4);
      gl_lds16(Bbase + (size_t)row * 512 + k0 * 2 + scb, (char*)Bl + o);
    }
    __syncthreads();
    #pragma unroll
    for (int ks = 0; ks < 2; ks++) {
      int koff = (ks * 64 + kg * 16) ^ swz;
      short8 af[2], bfr[4];
      #pragma unroll
      for (int mi = 0; mi < 2; mi++)
        af[mi] = *(const short8*)((const char*)Al + (w * 32 + mi * 16 + l15) * 128 + koff);
      #pragma unroll
      for (int ni = 0; ni < 4; ni++)
        bfr[ni] = *(const short8*)((const char*)Bl + (ni * 16 + l15) * 128 + koff);
      #pragma unroll
      for (int mi = 0; mi < 2; mi++)
        #pragma unroll
        for (int ni = 0; ni < 4; ni++)
          acc[mi][ni] = __builtin_amdgcn_mfma_f32_16x16x32_bf16(af[mi], bfr[ni], acc[mi][ni], 0, 0, 0);
    }
    __syncthreads();
  }
  // phase 2a: Q (+bias) -> QL [128][68]
  #pragma unroll
  for (int ni = 0; ni < 4; ni++) {
    float bqv = bq[d0 + ni * 16 + l15];
    #pragma unroll
    for (int mi = 0; mi < 2; mi++) {
      f32x4 vv = acc[mi][ni];
      int m = w * 32 + mi * 16 + kg * 4;
      #pragma unroll
      for (int j = 0; j < 4; j++)
        QL[(m + j) * 68 + ni * 16 + l15] = vv[j] + bqv;
    }
  }
  __syncthreads();
  // phase 2b: ws-DFT as register-tiled GEMM; thread = (s, d-quad, f2-quad)
  {
    int s = tid >> 7, dq = (tid >> 3) & 15, f2q = tid & 7;
    float a2[4][4];
    #pragma unroll
    for (int i = 0; i < 4; i++)
      #pragma unroll
      for (int j = 0; j < 4; j++) a2[i][j] = 0.f;
    const float* qbase = &QL[(s * 64) * 68 + dq * 4];
    const float* wbase = &WL[f2q * 4];
    #pragma unroll 8
    for (int wsx = 0; wsx < 64; wsx++) {
      float4 qv = *reinterpret_cast<const float4*>(qbase + wsx * 68);
      float4 wv = *reinterpret_cast<const float4*>(wbase + wsx * 32);
      a2[0][0] += qv.x * wv.x; a2[0][1] += qv.x * wv.y; a2[0][2] += qv.x * wv.z; a2[0][3] += qv.x * wv.w;
      a2[1][0] += qv.y * wv.x; a2[1][1] += qv.y * wv.y; a2[1][2] += qv.y * wv.z; a2[1][3] += qv.y * wv.w;
      a2[2][0] += qv.z * wv.x; a2[2][1] += qv.z * wv.y; a2[2][2] += qv.z * wv.z; a2[2][3] += qv.z * wv.w;
      a2[3][0] += qv.w * wv.x; a2[3][1] += qv.w * wv.y; a2[3][2] += qv.w * wv.z; a2[3][3] += qv.w * wv.w;
    }
    int sg = ((blockIdx.x & 255) << 1) + s;
    #pragma unroll
    for (int di = 0; di < 4; di++) {
      size_t gidx = ((size_t)(b * 512 + sg) * 256 + d0 + dq * 4 + di) * 32 + f2q * 4;
      *reinterpret_cast<float4*>(&Fwg[gidx]) = make_float4(a2[di][0], a2[di][1], a2[di][2], a2[di][3]);
    }
  }
}

// ---------------- K3f: per (b,d): t-DFT (in-place LDS) + selected hs-reduction -> X[bd][p][f] ----------------
__global__ __launch_bounds__(512) void k3f(const float* __restrict__ Fwg, const float* __restrict__ tab,
                                           const int* __restrict__ panel, float* __restrict__ X) {
  __shared__ float2 Floc[8192];   // 64 KB: [s=512][f=16] then in-place [kt=16][hs=32][f=16]
  __shared__ float2 fhT[32][64];  // 16 KB
  __shared__ float2 W16L[16][16]; // 2 KB
  __shared__ int ktl[64];
  int bd = blockIdx.x; int b = bd >> 8; int d = bd & 255;
  int tid = threadIdx.x;
  if (tid < 256) W16L[tid >> 4][tid & 15] = reinterpret_cast<const float2*>(tab + OFF_W16)[tid];
  for (int i = tid; i < 2048; i += 512) fhT[i >> 6][i & 63] = reinterpret_cast<const float2*>(tab + OFF_FHT)[i];
  if (tid < 64) ktl[tid] = panel[tid] >> 5;
  // stage this (b,d) column of Fw: 512 rows x 128 B, scattered global -> linear LDS
  {
    const char* gb = (const char*)Fwg;
    #pragma unroll
    for (int r = 0; r < 8; r++) {
      int o = r * 8192 + tid * 16;
      int s = o >> 7; int c16 = (o >> 4) & 7;
      size_t gaddr = ((size_t)(b * 512 + s) * 256 + d) * 128 + (size_t)c16 * 16;
      gl_lds16(gb + gaddr, (char*)Floc + o);
    }
  }
  __syncthreads();
  // t-phase: thread owns column (hs, f); in-place safe (column-private)
  int hs = tid >> 4, f = tid & 15;
  float2 v[16];
  #pragma unroll
  for (int t = 0; t < 16; t++) v[t] = Floc[(t * 32 + hs) * 16 + f];
  float2 a[16];
  #pragma unroll
  for (int k = 0; k < 16; k++) a[k] = make_float2(0.f, 0.f);
  #pragma unroll
  for (int t = 0; t < 16; t++) {
    float2 vv = v[t];
    #pragma unroll
    for (int k = 0; k < 16; k++) {
      float2 w = W16L[t][k];
      a[k].x += w.x * vv.x - w.y * vv.y;
      a[k].y += w.x * vv.y + w.y * vv.x;
    }
  }
  #pragma unroll
  for (int k = 0; k < 16; k++) Floc[(k * 32 + hs) * 16 + f] = a[k];
  __syncthreads();
  // hs-phase: thread handles p = p2 and p2+32 for its f
  int p2 = tid >> 4;
  float2 res[2];
  #pragma unroll
  for (int half = 0; half < 2; half++) {
    int p = p2 + half * 32;
    int kt = ktl[p];
    float ar = 0.f, ai = 0.f;
    #pragma unroll 8
    for (int h = 0; h < 32; h++) {
      float2 e = fhT[h][p];
      float2 u = Floc[(kt * 32 + h) * 16 + f];
      ar += u.x * e.x - u.y * e.y;
      ai += u.x * e.y + u.y * e.x;
    }
    res[half] = make_float2(ar, ai);
  }
  float2* Xo = reinterpret_cast<float2*>(X) + (size_t)bd * 1024;
  Xo[p2 * 16 + f] = res[0];
  Xo[(p2 + 32) * 16 + f] = res[1];
}

// ---------------- K3b: mode mix out_sel = sum_i x_sel * w ----------------
__global__ __launch_bounds__(512) void k3b_mix(const float* __restrict__ X, const float* __restrict__ wreal,
                                               const float* __restrict__ wimag, float* __restrict__ V) {
  __shared__ float2 xs[4][32][16];
  int h = blockIdx.x >> 6;
  int p = blockIdx.x & 63;
  int tid = threadIdx.x;
  const float2* Xv = reinterpret_cast<const float2*>(X);
  for (int i = tid; i < 2048; i += 512) {
    int b = i >> 9, ii = (i >> 4) & 31, f = i & 15;
    xs[b][ii][f] = Xv[((size_t)(b * 256 + h * 32 + ii) * MP + p) * ML + f];
  }
  __syncthreads();
  int o = tid >> 4, f = tid & 15;
  float accr[4] = {0, 0, 0, 0}, acci[4] = {0, 0, 0, 0};
  for (int i = 0; i < 32; i++) {
    size_t wofs = ((((size_t)h * 32 + i) * 32 + o) * MP + p) * ML + f;
    float wr = wreal[wofs], wi = wimag[wofs];
    #pragma unroll
    for (int b = 0; b < 4; b++) {
      float2 xv = xs[b][i][f];
      accr[b] += xv.x * wr - xv.y * wi;
      acci[b] += xv.x * wi + xv.y * wr;
    }
  }
  #pragma unroll
  for (int b = 0; b < 4; b++)
    reinterpret_cast<float2*>(V)[((size_t)(b * 256 + h * 32 + o) * MP + p) * ML + f] =
        make_float2(accr[b], acci[b]);
}

// ---------------- K4a: inverse spatial DFT -> G[b][c][s][f] (fp32, global) ----------------
__global__ __launch_bounds__(256) void k4a_inv(const float* __restrict__ V, const float* __restrict__ tab,
                                               float* __restrict__ gbuf) {
  __shared__ float2 vl[64][16];
  __shared__ float2 ft[64][16];
  __shared__ float2 fh[64][32];
  int bd = blockIdx.x;
  int tid = threadIdx.x;
  const float2* Vv = reinterpret_cast<const float2*>(V) + (size_t)bd * MP * ML;
  for (int i = tid; i < 1024; i += 256) {
    vl[i >> 4][i & 15] = Vv[i];
    ft[i >> 4][i & 15] = make_float2(tab[OFF_FTRE + i], tab[OFF_FTIM + i]);
  }
  for (int i = tid; i < 2048; i += 256) fh[i >> 5][i & 31] = make_float2(tab[OFF_FHRE + i], tab[OFF_FHIM + i]);
  __syncthreads();
  float g0[16], g1[16];
  #pragma unroll
  for (int f = 0; f < 16; f++) { g0[f] = 0.f; g1[f] = 0.f; }
  int s0 = tid * 2;
  int t0 = s0 >> 5, hs0 = s0 & 31;
  int t1 = (s0 + 1) >> 5, hs1 = (s0 + 1) & 31;
  for (int p = 0; p < 64; p++) {
    float2 et0 = ft[p][t0], eh0 = fh[p][hs0];
    float2 et1 = ft[p][t1], eh1 = fh[p][hs1];
    float er0 = et0.x * eh0.x - et0.y * eh0.y;
    float ei0 = et0.x * eh0.y + et0.y * eh0.x;
    float er1 = et1.x * eh1.x - et1.y * eh1.y;
    float ei1 = et1.x * eh1.y + et1.y * eh1.x;
    #pragma unroll
    for (int f = 0; f < 16; f++) {
      float2 v = vl[p][f];
      g0[f] += v.x * er0 + v.y * ei0;
      g1[f] += v.x * er1 + v.y * ei1;
    }
  }
  float4* gb = reinterpret_cast<float4*>(gbuf + (size_t)bd * 8192 + (size_t)s0 * 16);
  #pragma unroll
  for (int q = 0; q < 4; q++)
    gb[q] = make_float4(g0[q * 4] * (1.f / 512.f), g0[q * 4 + 1] * (1.f / 512.f),
                        g0[q * 4 + 2] * (1.f / 512.f), g0[q * 4 + 3] * (1.f / 512.f));
  #pragma unroll
  for (int q = 0; q < 4; q++)
    gb[4 + q] = make_float4(g1[q * 4] * (1.f / 512.f), g1[q * 4 + 1] * (1.f / 512.f),
                            g1[q * 4 + 2] * (1.f / 512.f), g1[q * 4 + 3] * (1.f / 512.f));
}

// ---------------- K4b: o[b][sp][c] bf16 = sum_f G[b][c][s][f] * cw[f][ws] ----------------
__global__ __launch_bounds__(256) void k4b_cos(const float* __restrict__ gbuf, const float* __restrict__ tab,
                                               unsigned short* __restrict__ ob) {
  __shared__ float Gs[256][17];
  __shared__ float cwL[16][64];
  int s = blockIdx.x, b = blockIdx.y;
  int tid = threadIdx.x;
  for (int i = tid; i < 4096; i += 256) {
    int c = i >> 4, f = i & 15;
    Gs[c][f] = gbuf[(size_t)(b * 256 + c) * 8192 + s * 16 + f];
  }
  for (int i = tid; i < 1024; i += 256) cwL[i >> 6][i & 63] = tab[OFF_CW + i];
  __syncthreads();
  int c0 = (tid & 63) * 4, wsg = tid >> 6;
  float gv[4][16];
  #pragma unroll
  for (int j = 0; j < 4; j++)
    #pragma unroll
    for (int f = 0; f < 16; f++) gv[j][f] = Gs[c0 + j][f];
  for (int wsi = 0; wsi < 16; wsi++) {
    int wsx = wsg * 16 + wsi;
    float a0 = 0.f, a1 = 0.f, a2 = 0.f, a3 = 0.f;
    #pragma unroll
    for (int f = 0; f < 16; f++) {
      float cwv = cwL[f][wsx];
      a0 += gv[0][f] * cwv; a1 += gv[1][f] * cwv; a2 += gv[2][f] * cwv; a3 += gv[3][f] * cwv;
    }
    ushort4 u;
    u.x = f2bf(a0); u.y = f2bf(a1); u.z = f2bf(a2); u.w = f2bf(a3);
    *reinterpret_cast<ushort4*>(&ob[((size_t)b * SPAT + (size_t)s * 64 + wsx) * 256 + c0]) = u;
  }
}

// ---------------- K5: out = o @ Wo + bo via bf16 MFMA, out fp32 [b][sp][d] ----------------
__global__ __launch_bounds__(256) void k5_mfma(const unsigned short* __restrict__ ob,
                                               const unsigned short* __restrict__ wot,
                                               const float* __restrict__ bo, float* __restrict__ out) {
  __shared__ char smem[34816];
  unsigned short* Al = (unsigned short*)smem;           // 16384 B
  unsigned short* Bl = (unsigned short*)(smem + 16384); // 8192 B
  float* OL = (float*)smem;                             // [128][68] fp32 epilogue overlay
  int b = blockIdx.x >> 8, sp0 = (blockIdx.x & 255) << 7, d0 = blockIdx.y << 6;
  int tid = threadIdx.x;
  int lane = tid & 63, w = tid >> 6;
  int l15 = lane & 15, kg = lane >> 4;
  int swz = (l15 & 7) << 4;
  f32x4 acc[2][4];
  #pragma unroll
  for (int mi = 0; mi < 2; mi++)
    #pragma unroll
    for (int ni = 0; ni < 4; ni++) acc[mi][ni] = (f32x4){0.f, 0.f, 0.f, 0.f};
  const char* Abase = (const char*)(ob + ((size_t)b * 32768 + sp0) * 256);
  const char* Bbase = (const char*)(wot + (size_t)d0 * 256);
  for (int k0 = 0; k0 < 256; k0 += 64) {
    #pragma unroll
    for (int it = 0; it < 4; it++) {
      int o = tid * 16 + it * 4096;
      int row = o >> 7, cb = o & 127;
      int scb = cb ^ ((row & 7) << 4);
      gl_lds16(Abase + (size_t)row * 512 + k0 * 2 + scb, (char*)Al + o);
    }
    #pragma unroll
    for (int it = 0; it < 2; it++) {
      int o = tid * 16 + it * 4096;
      int row = o >> 7, cb = o & 127;
      int scb = cb ^ ((row & 7) << 4);
      gl_lds16(Bbase + (size_t)row * 512 + k0 * 2 + scb, (char*)Bl + o);
    }
    __syncthreads();
    #pragma unroll
    for (int ks = 0; ks < 2; ks++) {
      int koff = (ks * 64 + kg * 16) ^ swz;
      short8 af[2], bfr[4];
      #pragma unroll
      for (int mi = 0; mi < 2; mi++)
        af[mi] = *(const short8*)((const char*)Al + (w * 32 + mi * 16 + l15) * 128 + koff);
      #pragma unroll
      for (int ni = 0; ni < 4; ni++)
        bfr[ni] = *(const short8*)((const char*)Bl + (ni * 16 + l15) * 128 + koff);
      #pragma unroll
      for (int mi = 0; mi < 2; mi++)
        #pragma unroll
        for (int ni = 0; ni < 4; ni++)
          acc[mi][ni] = __builtin_amdgcn_mfma_f32_16x16x32_bf16(af[mi], bfr[ni], acc[mi][ni], 0, 0, 0);
    }
    __syncthreads();
  }
  // epilogue: acc(+bias) -> OL [128][68] -> coalesced float4 stores (256B segments)
  #pragma unroll
  for (int ni = 0; ni < 4; ni++) {
    float bov = bo[d0 + ni * 16 + l15];
    #pragma unroll
    for (int mi = 0; mi < 2; mi++) {
      f32x4 v = acc[mi][ni];
      int m = w * 32 + mi * 16 + kg * 4;
      #pragma unroll
      for (int j = 0; j < 4; j++)
        OL[(m + j) * 68 + ni * 16 + l15] = v[j] + bov;
    }
  }
  __syncthreads();
  int f4 = tid & 15, r0 = tid >> 4;
  #pragma unroll
  for (int r = 0; r < 8; r++) {
    int m = r * 16 + r0;
    float4 val = *reinterpret_cast<const float4*>(&OL[m * 68 + f4 * 4]);
    *reinterpret_cast<float4*>(&out[((size_t)b * SPAT + sp0 + m) * 256 + d0 + f4 * 4]) = val;
  }
}

extern "C" void kernel_launch(void* const* d_in, const int* in_sizes, int n_in,
                              void* d_out, int out_size, void* d_ws, size_t ws_size,
                              hipStream_t stream) {
  const float* x  = (const float*)d_in[0];
  const float* Wq = (const float*)d_in[1];
  const float* bq = (const float*)d_in[2];
  // d_in[3..6] = Wk,bk,Wv,bv -- dead in the reference, skipped
  const float* Wo = (const float*)d_in[7];
  const float* bo = (const float*)d_in[8];
  const float* wr = (const float*)d_in[9];
  const float* wi = (const float*)d_in[10];
  const int* panel = (const int*)d_in[11];
  float* ws = (float*)d_ws;
  float* out = (float*)d_out;

  unsigned short* xb   = (unsigned short*)(ws + OFF_XB);             // dead after k1f
  float*          gbuf = ws + OFF_XB;                                // reuses xb region (k4a onward)
  unsigned short* obb  = (unsigned short*)(ws + OFF_XB + 8388608);   // reuses xb region 2nd half
  unsigned short* wqt  = (unsigned short*)(ws + OFF_WT);
  unsigned short* wot  = wqt + 65536;

  hipLaunchKernelGGL(k0_tables, dim3(1), dim3(256), 0, stream, panel, ws);
  hipLaunchKernelGGL(conv_w, dim3(8, 8, 2), dim3(256), 0, stream, Wq, Wo, wqt, wot);
  hipLaunchKernelGGL(conv_x, dim3(16384), dim3(256), 0, stream, x, xb);
  hipLaunchKernelGGL(k1f, dim3(1024, 4), dim3(256), 0, stream, xb, wqt, bq, ws, ws + OFF_FW);
  hipLaunchKernelGGL(k3f, dim3(1024), dim3(512), 0, stream, ws + OFF_FW, ws, panel, ws + OFF_X);
  hipLaunchKernelGGL(k3b_mix, dim3(512), dim3(512), 0, stream, ws + OFF_X, wr, wi, ws + OFF_V);
  hipLaunchKernelGGL(k4a_inv, dim3(1024), dim3(256), 0, stream, ws + OFF_V, ws, gbuf);
  hipLaunchKernelGGL(k4b_cos, dim3(512, 4), dim3(256), 0, stream, gbuf, ws, obb);
  hipLaunchKernelGGL(k5_mfma, dim3(1024, 4), dim3(256), 0, stream, obb, wot, bo, out);
}